// Round 9
// baseline (533.365 us; speedup 1.0000x reference)
//
#include <hip/hip_runtime.h>
#include <math.h>
#include <float.h>

#define BB 32
#define CC 64
#define KK 8192
#define NPIX 256
#define NELEM (BB*CC*NPIX)  // 524288

typedef unsigned short u16;
typedef __attribute__((ext_vector_type(8))) short bf16x8;
typedef __attribute__((ext_vector_type(4))) float f32x4;

__device__ __forceinline__ u16 f2bf(float v) {   // RNE f32->bf16
  unsigned u = __float_as_uint(v);
  return (u16)((u + 0x7FFFu + ((u >> 16) & 1u)) >> 16);
}

// init zr/out + wsq + ehi(bf16 pack of emb) in one launch
__global__ void k_prep(const float* __restrict__ f, float* __restrict__ zr,
                       float* __restrict__ out, const float* __restrict__ emb,
                       float* __restrict__ wsq32, u16* __restrict__ ehi) {
  int i = blockIdx.x * 256 + threadIdx.x;
  if (i < NELEM) { zr[i] = f[i]; out[i] = 0.f; ehi[i] = f2bf(emb[i]); }
  if (i < KK) {
    const float* row = emb + i * 64;
    double s = 0.0;
    #pragma unroll
    for (int c = 0; c < 64; ++c) s += (double)row[c] * (double)row[c];
    wsq32[i] = (float)s;   // same-binade f32: argmin-safe (scheme-free)
  }
}

// numpy-exact area mean (pairwise row sums, sequential dy, exact pow2 scale)
__global__ void k_down(const float* __restrict__ zr, float* __restrict__ zd, int pn) {
#pragma clang fp contract(off)
  int i = blockIdx.x * 256 + threadIdx.x;
  int pnpn = pn * pn;
  int n = BB * CC * pnpn;
  if (i >= n) return;
  int x = i % pn; int y = (i / pn) % pn; int bc = i / pnpn;
  int bs = 16 / pn;
  const float* src = zr + bc * NPIX + (y * bs) * 16 + x * bs;
  float acc = 0.f;
  for (int dy = 0; dy < bs; ++dy) {
    const float* a = src + dy * 16;
    float s;
    if (bs == 16) {
      float r[8];
      #pragma unroll
      for (int j = 0; j < 8; ++j) r[j] = a[j] + a[8 + j];
      s = ((r[0] + r[1]) + (r[2] + r[3])) + ((r[4] + r[5]) + (r[6] + r[7]));
    } else if (bs == 8) {
      s = ((a[0] + a[1]) + (a[2] + a[3])) + ((a[4] + a[5]) + (a[6] + a[7]));
    } else if (bs == 4) {
      s = ((a[0] + a[1]) + a[2]) + a[3];
    } else {
      s = a[0] + a[1];
    }
    acc = acc + s;
  }
  zd[i] = acc * (1.f / (bs * bs));
}

// pack z -> bf16 [vec][c] + zsq (f64->f32). numVec multiple of 256.
__global__ void k_zpack(const float* __restrict__ zsrc, int pnpn,
                        u16* __restrict__ zhi, float* __restrict__ zsq32) {
  int vec = blockIdx.x * 256 + threadIdx.x;
  int b = vec / pnpn, p = vec - b * pnpn;
  const float* zp = zsrc + (size_t)b * 64 * pnpn + p;
  u16* zo = zhi + (size_t)vec * 64;
  double s = 0.0;
  #pragma unroll 8
  for (int c = 0; c < 64; ++c) {
    float v = zp[(size_t)c * pnpn];
    s = fma((double)v, (double)v, s);
    zo[c] = f2bf(v);
  }
  zsq32[vec] = (float)s;
}

// ---- argmin, small scales (exact path, proven) ----
__global__ __launch_bounds__(256, 4) void k_argmin(
    const float* __restrict__ zd, const float* __restrict__ emb,
    const float* __restrict__ wsq32,
    float* __restrict__ pd, int* __restrict__ pi,
    int numVec, int pnpn, int kchunk) {
#pragma clang fp contract(off)
  __shared__ __align__(16) float zt[32][68];
  __shared__ __align__(16) float et[64 * 64];
  __shared__ float ws_s[64];
  __shared__ float red_d[256];
  __shared__ int   red_i[256];
  int tid = threadIdx.x;
  int v0 = blockIdx.x * 32;
  int kbase = blockIdx.y * kchunk;

  for (int idx = tid; idx < 32 * 64; idx += 256) {
    int v = idx >> 6, c = idx & 63;
    int vi = v0 + v;
    float val = 0.f;
    if (vi < numVec) {
      int b = vi / pnpn, p = vi % pnpn;
      val = zd[(b * 64 + c) * pnpn + p];
    }
    zt[v][c] = val;
  }
  __syncthreads();

  const int v = tid & 31, kg = tid >> 5;
  float4 z4[16];
  #pragma unroll
  for (int i = 0; i < 16; ++i) z4[i] = *reinterpret_cast<float4*>(&zt[v][i * 4]);
  float zsq = 0.f;
  #pragma unroll
  for (int i = 0; i < 16; ++i)
    zsq += z4[i].x * z4[i].x + z4[i].y * z4[i].y + z4[i].z * z4[i].z + z4[i].w * z4[i].w;

  float bd = FLT_MAX; int bi = 0x7fffffff;
  for (int k0 = 0; k0 < kchunk; k0 += 64) {
    __syncthreads();
    {
      const float4* gsrc = reinterpret_cast<const float4*>(emb + (size_t)(kbase + k0) * 64);
      float4* ldst = reinterpret_cast<float4*>(et);
      #pragma unroll
      for (int idx = 0; idx < 4; ++idx)
        ldst[tid + idx * 256] = gsrc[tid + idx * 256];
    }
    if (tid < 64) ws_s[tid] = wsq32[kbase + k0 + tid];
    __syncthreads();
    #pragma unroll
    for (int j = 0; j < 8; ++j) {
      int kl = kg * 8 + j;
      const float4* e4 = reinterpret_cast<const float4*>(&et[kl * 64]);
      float acc = 0.f;
      #pragma unroll
      for (int i = 0; i < 16; ++i) {
        float4 e = e4[i];
        acc = __builtin_fmaf(z4[i].x, e.x, acc);
        acc = __builtin_fmaf(z4[i].y, e.y, acc);
        acc = __builtin_fmaf(z4[i].z, e.z, acc);
        acc = __builtin_fmaf(z4[i].w, e.w, acc);
      }
      float t1 = zsq + ws_s[kl];
      float d  = t1 - 2.0f * acc;
      if (d < bd) { bd = d; bi = kbase + k0 + kl; }
    }
  }
  red_d[tid] = bd; red_i[tid] = bi;
  __syncthreads();
  if (tid < 32) {
    float fb = red_d[tid]; int fi = red_i[tid];
    #pragma unroll
    for (int g = 1; g < 8; ++g) {
      float cd = red_d[g * 32 + tid]; int ci = red_i[g * 32 + tid];
      if (cd < fb || (cd == fb && ci < fi)) { fb = cd; fi = ci; }
    }
    int vi = v0 + tid;
    if (vi < numVec) {
      pd[blockIdx.y * numVec + vi] = fb;
      pi[blockIdx.y * numVec + vi] = fi;
    }
  }
}

// ---- argmin big scales: bf16 MFMA prefilter. grid (numVec/128, KS).
// wave: 32 vecs (2 sets of 16) x part codes; top-3/column -> top-4/part.
#define INS4(dd, ii)                                                   \
  { bool c0 = (dd) < q0, c1 = (dd) < q1, c2 = (dd) < q2, c3 = (dd) < q3; \
    q3 = c2 ? q2 : (c3 ? (dd) : q3); j3 = c2 ? j2 : (c3 ? (ii) : j3);  \
    q2 = c1 ? q1 : (c2 ? (dd) : q2); j2 = c1 ? j1 : (c2 ? (ii) : j2);  \
    q1 = c0 ? q0 : (c1 ? (dd) : q1); j1 = c0 ? j0 : (c1 ? (ii) : j1);  \
    q0 = c0 ? (dd) : q0;             j0 = c0 ? (ii) : j0; }

__global__ __launch_bounds__(256, 4) void k_argmin_mfma(
    const u16* __restrict__ zhi, const float* __restrict__ zsq32,
    const u16* __restrict__ ehi, const float* __restrict__ wsq32,
    float* __restrict__ cdp, int* __restrict__ cip,
    int numVec, int part) {
  __shared__ u16  es[2][64 * 72];   // code stride 72 (pad) -> 2-way max on reads
  __shared__ float wss[2][64];
  const int tid = threadIdx.x;
  const int wid = tid >> 6, lane = tid & 63;
  const int l15 = lane & 15, l4 = lane >> 4;
  const int vw = blockIdx.x * 128 + wid * 32;
  const int kbase = blockIdx.y * part;

  // A-frags (z) + zsq, in regs for the whole kernel
  bf16x8 za[2][2];
  f32x4 zq[2];
  #pragma unroll
  for (int s = 0; s < 2; ++s) {
    const u16* zp = zhi + (size_t)(vw + s * 16 + l15) * 64 + l4 * 8;
    za[s][0] = *reinterpret_cast<const bf16x8*>(zp);
    za[s][1] = *reinterpret_cast<const bf16x8*>(zp + 32);
    zq[s] = *reinterpret_cast<const f32x4*>(zsq32 + vw + s * 16 + l4 * 4);
  }

  float d1[2][4], d2[2][4], d3[2][4];
  int   i1[2][4], i2[2][4], i3[2][4];
  #pragma unroll
  for (int s = 0; s < 2; ++s)
    #pragma unroll
    for (int r = 0; r < 4; ++r) {
      d1[s][r] = FLT_MAX; d2[s][r] = FLT_MAX; d3[s][r] = FLT_MAX;
      i1[s][r] = 0x7fffffff; i2[s][r] = 0x7fffffff; i3[s][r] = 0x7fffffff;
    }

  const int NT = part >> 6;
  // stage super-tile t into buf
  #define STAGE(buf, t)                                                      \
    { const u16* src = ehi + (size_t)(kbase + (t) * 64) * 64;                \
      int code = tid >> 2, seg = tid & 3;                                    \
      const bf16x8* s8 = reinterpret_cast<const bf16x8*>(src + code * 64 + seg * 16); \
      bf16x8 v0 = s8[0], v1 = s8[1];                                         \
      bf16x8* d8 = reinterpret_cast<bf16x8*>(&es[buf][code * 72 + seg * 16]);\
      d8[0] = v0; d8[1] = v1;                                                \
      if (tid < 64) wss[buf][tid] = wsq32[kbase + (t) * 64 + tid]; }

  STAGE(0, 0);
  __syncthreads();
  for (int t = 0; t < NT; ++t) {
    int cur = t & 1;
    if (t + 1 < NT) { STAGE(cur ^ 1, t + 1); }
    #pragma unroll
    for (int ct = 0; ct < 4; ++ct) {
      const u16* eb = &es[cur][(ct * 16 + l15) * 72 + l4 * 8];
      bf16x8 b0 = *reinterpret_cast<const bf16x8*>(eb);
      bf16x8 b1 = *reinterpret_cast<const bf16x8*>(eb + 32);
      float wl = wss[cur][ct * 16 + l15];
      int ki = kbase + t * 64 + ct * 16 + l15;
      #pragma unroll
      for (int s = 0; s < 2; ++s) {
        f32x4 acc = {0.f, 0.f, 0.f, 0.f};
        acc = __builtin_amdgcn_mfma_f32_16x16x32_bf16(za[s][0], b0, acc, 0, 0, 0);
        acc = __builtin_amdgcn_mfma_f32_16x16x32_bf16(za[s][1], b1, acc, 0, 0, 0);
        #pragma unroll
        for (int r = 0; r < 4; ++r) {
          float t1 = zq[s][r] + wl;
          float d  = fmaf(acc[r], -2.f, t1);
          bool c0 = d < d1[s][r], c1b = d < d2[s][r], c2b = d < d3[s][r];
          d3[s][r] = c1b ? d2[s][r] : (c2b ? d  : d3[s][r]);
          i3[s][r] = c1b ? i2[s][r] : (c2b ? ki : i3[s][r]);
          d2[s][r] = c0 ? d1[s][r] : (c1b ? d  : d2[s][r]);
          i2[s][r] = c0 ? i1[s][r] : (c1b ? ki : i2[s][r]);
          d1[s][r] = c0 ? d  : d1[s][r];
          i1[s][r] = c0 ? ki : i1[s][r];
        }
      }
    }
    __syncthreads();
  }

  // cross-column merge to part top-4, write out
  #pragma unroll
  for (int s = 0; s < 2; ++s)
    #pragma unroll
    for (int r = 0; r < 4; ++r) {
      float q0 = d1[s][r], q1 = d2[s][r], q2 = d3[s][r], q3 = FLT_MAX;
      int   j0 = i1[s][r], j1 = i2[s][r], j2 = i3[s][r], j3 = 0x7fffffff;
      #pragma unroll
      for (int m = 1; m < 16; m <<= 1) {
        float p0 = __shfl_xor(q0, m), p1 = __shfl_xor(q1, m);
        float p2 = __shfl_xor(q2, m), p3 = __shfl_xor(q3, m);
        int   o0 = __shfl_xor(j0, m), o1 = __shfl_xor(j1, m);
        int   o2 = __shfl_xor(j2, m), o3 = __shfl_xor(j3, m);
        INS4(p0, o0); INS4(p1, o1); INS4(p2, o2); INS4(p3, o3);
      }
      if (l15 == 0) {
        int vec = vw + s * 16 + l4 * 4 + r;
        size_t base = ((size_t)blockIdx.y * numVec + vec) * 4;
        cdp[base + 0] = q0; cdp[base + 1] = q1; cdp[base + 2] = q2; cdp[base + 3] = q3;
        cip[base + 0] = j0; cip[base + 1] = j1; cip[base + 2] = j2; cip[base + 3] = j3;
      }
    }
}

// exact (numpy-f32-chain) rescore of in-band candidates; writes tok via pd/pi(ksplit=1)
__global__ void k_rescore(
    const float* __restrict__ cdp, const int* __restrict__ cip,
    const float* __restrict__ zsrc, const float* __restrict__ emb,
    const float* __restrict__ wsq32, const float* __restrict__ zsq32,
    float* __restrict__ pd, int* __restrict__ pi,
    int numVec, int pnpn, int ksplit) {
#pragma clang fp contract(off)
  int vec = blockIdx.x * 256 + threadIdx.x;
  if (vec >= numVec) return;
  float zsq = zsq32[vec];
  int ncand = ksplit * 4;
  float dmin = FLT_MAX;
  for (int e = 0; e < ncand; ++e) {
    float dv = cdp[((size_t)(e >> 2) * numVec + vec) * 4 + (e & 3)];
    dmin = fminf(dmin, dv);
  }
  float band = dmin + fmaf(sqrtf(zsq), 1.25e-5f, 1e-4f);  // covers bf16 err + bin quant
  int b = vec / pnpn, p = vec - b * pnpn;
  const float* zp = zsrc + (size_t)b * 64 * pnpn + p;
  float bd = FLT_MAX; int bi = 0x7fffffff;
  for (int e = 0; e < ncand; ++e) {
    size_t off = ((size_t)(e >> 2) * numVec + vec) * 4 + (e & 3);
    float dv = cdp[off];
    if (dv > band) continue;
    int ki = cip[off];
    const float* er = emb + (size_t)ki * 64;
    float acc = 0.f;
    #pragma unroll 8
    for (int c = 0; c < 64; ++c)
      acc = __builtin_fmaf(zp[(size_t)c * pnpn], er[c], acc);
    float t1 = zsq + wsq32[ki];
    float d  = t1 - 2.0f * acc;
    if (d < bd || (d == bd && ki < bi)) { bd = d; bi = ki; }
  }
  pd[vec] = 0.f;
  pi[vec] = bi;
}

// ---- fused ksplit-reduce + cubic upsample ----
__global__ __launch_bounds__(256) void k_up(
    const float* __restrict__ pd, const int* __restrict__ pi,
    const float* __restrict__ emb, float* __restrict__ hup,
    int pn, int ksplit) {
  __shared__ float td[256];
  __shared__ int   ti[256];
  __shared__ int   tok_s[256];
  __shared__ float wsh[16][4];
  __shared__ int   i0sh[16];

  int t = threadIdx.x;
  int i = blockIdx.x * 256 + t;
  int p = i & 255; int c = (i >> 8) & 63; int b = i >> 14;
  int P = pn * pn;
  int numVec = BB * P;
  int R = 256 / P;
  int v = t % P, sg = t / P;

  float bd = FLT_MAX; int bi = 0x7fffffff;
  for (int s = sg; s < ksplit; s += R) {
    float cd = pd[s * numVec + b * P + v]; int ci = pi[s * numVec + b * P + v];
    if (cd < bd || (cd == bd && ci < bi)) { bd = cd; bi = ci; }
  }
  td[t] = bd; ti[t] = bi;
  __syncthreads();
  for (int r = R >> 1; r >= 1; r >>= 1) {
    if (sg < r) {
      float cd = td[t + r * P]; int ci = ti[t + r * P];
      if (cd < td[t] || (cd == td[t] && ci < ti[t])) { td[t] = cd; ti[t] = ci; }
    }
    __syncthreads();
  }
  if (t < P) tok_s[t] = ti[t];
  if (pn < 16 && t < 16) {
    double s = (t + 0.5) * ((double)pn / 16.0) - 0.5;
    int i0 = (int)floor(s) - 1;
    int hi = pn - 4; if (hi < 0) hi = 0;
    if (i0 < 0) i0 = 0; if (i0 > hi) i0 = hi;
    double wv[4]; double sum = 0.0;
    #pragma unroll
    for (int qq = 0; qq < 4; ++qq) {
      int ii = i0 + qq;
      double w = 0.0;
      if (ii < pn) {
        double xx = fabs(s - (double)ii);
        if (xx < 1.0)       w = ((1.5 * xx - 2.5) * xx) * xx + 1.0;
        else if (xx < 2.0)  w = ((-0.5 * xx + 2.5) * xx - 4.0) * xx + 2.0;
      }
      wv[qq] = w; sum += w;
    }
    i0sh[t] = i0;
    #pragma unroll
    for (int qq = 0; qq < 4; ++qq) wsh[t][qq] = (float)(wv[qq] / sum);
  }
  __syncthreads();

  if (pn == 16) { hup[i] = emb[(size_t)tok_s[p] * 64 + c]; return; }

  int y = p >> 4, x = p & 15;
  int iy0 = i0sh[y], ix0 = i0sh[x];
  float acc = 0.f;
  #pragma unroll
  for (int ty = 0; ty < 4; ++ty) {
    float wy = wsh[y][ty];
    int iy = iy0 + ty; if (iy > pn - 1) iy = pn - 1;
    float tmp = 0.f;
    #pragma unroll
    for (int tx = 0; tx < 4; ++tx) {
      float wx = wsh[x][tx];
      int ix = ix0 + tx; if (ix > pn - 1) ix = pn - 1;
      tmp += wx * emb[(size_t)tok_s[iy * pn + ix] * 64 + c];
    }
    acc += wy * tmp;
  }
  hup[i] = acc;
}

// ---- conv (round-8 proven version) ----
__global__ __launch_bounds__(256) void k_conv(
    const float* __restrict__ hup, const float* __restrict__ w,
    const float* __restrict__ bias, float* __restrict__ out, float* __restrict__ zr) {
  __shared__ __align__(16) float ins[16][18 * 18];
  __shared__ __align__(16) float wsh[8 * 64 * 12];
  int tid = threadIdx.x;
  int b = blockIdx.x;
  int ocb = blockIdx.y;

  for (int idx = tid; idx < 16 * 324; idx += 256)
    (&ins[0][0])[idx] = 0.f;
  for (int idx = tid; idx < 8 * 64 * 9; idx += 256) {
    int ocic = idx / 9, t = idx - ocic * 9;
    wsh[ocic * 12 + t] = w[(size_t)ocb * 8 * 64 * 9 + idx];
  }

  const int wid = tid >> 6, lane = tid & 63;
  const int ocg = wid >> 1;
  const int ph = (wid & 1) * 64 + lane;
  const int x = ph & 15, y2 = ph >> 4;

  float acc[4][2];
  #pragma unroll
  for (int j = 0; j < 4; ++j) {
    float bv = bias[ocb * 8 + ocg * 4 + j];
    acc[j][0] = bv; acc[j][1] = bv;
  }

  const float* hb = hup + (size_t)b * 64 * NPIX;
  float sreg[16];
  #pragma unroll
  for (int r = 0; r < 16; ++r) sreg[r] = hb[r * 256 + tid];

  for (int cc = 0; cc < 4; ++cc) {
    __syncthreads();
    #pragma unroll
    for (int r = 0; r < 16; ++r) {
      int idx = r * 256 + tid;
      int icl = idx >> 8, p = idx & 255;
      ins[icl][((p >> 4) + 1) * 18 + (p & 15) + 1] = sreg[r];
    }
    __syncthreads();
    if (cc < 3) {
      #pragma unroll
      for (int r = 0; r < 16; ++r) sreg[r] = hb[(cc + 1) * 4096 + r * 256 + tid];
    }

    #pragma unroll 2
    for (int icl = 0; icl < 16; ++icl) {
      float vt[4][3];
      const float* ip = &ins[icl][y2 * 2 * 18 + x];
      #pragma unroll
      for (int r = 0; r < 4; ++r)
        #pragma unroll
        for (int cxx = 0; cxx < 3; ++cxx)
          vt[r][cxx] = ip[r * 18 + cxx];

      int ic = cc * 16 + icl;
      #pragma unroll
      for (int j = 0; j < 4; ++j) {
        const float* wp = &wsh[((ocg * 4 + j) * 64 + ic) * 12];
        float4 wa = *reinterpret_cast<const float4*>(wp);
        float4 wb = *reinterpret_cast<const float4*>(wp + 4);
        float w8 = wp[8];
        float wv[9] = {wa.x, wa.y, wa.z, wa.w, wb.x, wb.y, wb.z, wb.w, w8};
        float a0 = acc[j][0], a1 = acc[j][1];
        #pragma unroll
        for (int dy = 0; dy < 3; ++dy)
          #pragma unroll
          for (int dx = 0; dx < 3; ++dx) {
            float wt = wv[dy * 3 + dx];
            a0 = __builtin_fmaf(vt[dy][dx], wt, a0);
            a1 = __builtin_fmaf(vt[dy + 1][dx], wt, a1);
          }
        acc[j][0] = a0; acc[j][1] = a1;
      }
    }
  }

  #pragma unroll
  for (int j = 0; j < 4; ++j) {
    int oc = ocb * 8 + ocg * 4 + j;
    #pragma unroll
    for (int r = 0; r < 2; ++r) {
      size_t gi = ((size_t)b * 64 + oc) * NPIX + (y2 * 2 + r) * 16 + x;
      float h = hup[gi];
      float ho = 0.5f * h + 0.5f * acc[j][r];
      out[gi] += ho;
      zr[gi]  -= ho;
    }
  }
}

extern "C" void kernel_launch(void* const* d_in, const int* in_sizes, int n_in,
                              void* d_out, int out_size, void* d_ws, size_t ws_size,
                              hipStream_t stream) {
  const float* f    = (const float*)d_in[0];
  const float* emb  = (const float*)d_in[1];
  const float* phiw = (const float*)d_in[2];
  const float* phib = (const float*)d_in[3];
  float* out = (float*)d_out;

  float* ws  = (float*)d_ws;
  float* zr     = ws;                        // 524288
  float* zd     = ws + 524288;               // 524288
  float* hup    = ws + 1048576;              // 524288
  float* wsq32  = ws + 1572864;              // 8192
  float* pd     = ws + 1581056;              // 65536
  int*   pi     = (int*)(ws + 1646592);      // 65536
  u16*   zhi    = (u16*)(ws + 1712128);      // 524288 u16 = 262144 f
  u16*   ehi    = (u16*)(ws + 1974272);      // 524288 u16 = 262144 f
  float* cand_d = ws + 2236416;              // 262144
  int*   cand_i = (int*)(ws + 2498560);      // 262144
  float* zsq32  = ws + 2760704;              // 8192
  // total ~11.1 MB

  // PHI_IDX (numpy linspace argmin in doubles)
  double start = 1.0 / 3.0 / 4.0;
  double stop  = 1.0 - 1.0 / 3.0 / 4.0;
  double step  = (stop - start) / 3.0;
  double ticks[4] = { start, 1.0 * step + start, 2.0 * step + start, stop };
  int phi_idx[5];
  for (int si = 0; si < 5; ++si) {
    double xx = si / 4.0;
    int bj = 0; double bdd = fabs(ticks[0] - xx);
    for (int j = 1; j < 4; ++j) { double dd = fabs(ticks[j] - xx); if (dd < bdd) { bdd = dd; bj = j; } }
    phi_idx[si] = bj;
  }

  static const int MSarr[5] = {1, 2, 4, 8, 16};

  k_prep<<<NELEM / 256, 256, 0, stream>>>(f, zr, out, emb, wsq32, ehi);

  const int KS[5] = {128, 32, 16, 32, 8};   // si>=3: parts for MFMA path
  for (int si = 0; si < 5; ++si) {
    int pn = MSarr[si], pnpn = pn * pn, numVec = BB * pnpn;
    const float* zsrc;
    if (si < 4) {
      int n = BB * CC * pnpn;
      k_down<<<(n + 255) / 256, 256, 0, stream>>>(zr, zd, pn);
      zsrc = zd;
    } else {
      zsrc = zr;
    }
    int ksplit = KS[si];
    if (si >= 3) {
      int part = KK / ksplit;
      k_zpack<<<numVec / 256, 256, 0, stream>>>(zsrc, pnpn, zhi, zsq32);
      dim3 g(numVec / 128, ksplit);
      k_argmin_mfma<<<g, 256, 0, stream>>>(zhi, zsq32, ehi, wsq32,
                                           cand_d, cand_i, numVec, part);
      k_rescore<<<numVec / 256, 256, 0, stream>>>(cand_d, cand_i, zsrc, emb,
                                                  wsq32, zsq32, pd, pi,
                                                  numVec, pnpn, ksplit);
      k_up<<<NELEM / 256, 256, 0, stream>>>(pd, pi, emb, hup, pn, 1);
    } else {
      int kchunk = KK / ksplit;
      dim3 g((numVec + 31) / 32, ksplit);
      k_argmin<<<g, 256, 0, stream>>>(zsrc, emb, wsq32, pd, pi, numVec, pnpn, kchunk);
      k_up<<<NELEM / 256, 256, 0, stream>>>(pd, pi, emb, hup, pn, ksplit);
    }
    int pidx = phi_idx[si];
    k_conv<<<dim3(BB, 8), 256, 0, stream>>>(hup, phiw + pidx * 64 * 64 * 9,
                                            phib + pidx * 64, out, zr);
  }
}

// Round 10
// 413.968 us; speedup vs baseline: 1.2884x; 1.2884x over previous
//
#include <hip/hip_runtime.h>
#include <math.h>
#include <float.h>

#define BB 32
#define CC 64
#define KK 8192
#define NPIX 256
#define NELEM (BB*CC*NPIX)  // 524288

typedef unsigned short u16;
typedef __attribute__((ext_vector_type(8))) short bf16x8;
typedef __attribute__((ext_vector_type(4))) float f32x4;

__device__ __forceinline__ u16 f2bf(float v) {   // RNE f32->bf16
  unsigned u = __float_as_uint(v);
  return (u16)((u + 0x7FFFu + ((u >> 16) & 1u)) >> 16);
}

// init zr/out + wsq + ehi(bf16 pack of emb) in one launch
__global__ void k_prep(const float* __restrict__ f, float* __restrict__ zr,
                       float* __restrict__ out, const float* __restrict__ emb,
                       float* __restrict__ wsq32, u16* __restrict__ ehi) {
  int i = blockIdx.x * 256 + threadIdx.x;
  if (i < NELEM) { zr[i] = f[i]; out[i] = 0.f; ehi[i] = f2bf(emb[i]); }
  if (i < KK) {
    const float* row = emb + i * 64;
    double s = 0.0;
    #pragma unroll
    for (int c = 0; c < 64; ++c) s += (double)row[c] * (double)row[c];
    wsq32[i] = (float)s;   // same-binade f32: argmin-safe (scheme-free)
  }
}

// numpy-exact area mean (pairwise row sums, sequential dy, exact pow2 scale)
__global__ void k_down(const float* __restrict__ zr, float* __restrict__ zd, int pn) {
#pragma clang fp contract(off)
  int i = blockIdx.x * 256 + threadIdx.x;
  int pnpn = pn * pn;
  int n = BB * CC * pnpn;
  if (i >= n) return;
  int x = i % pn; int y = (i / pn) % pn; int bc = i / pnpn;
  int bs = 16 / pn;
  const float* src = zr + bc * NPIX + (y * bs) * 16 + x * bs;
  float acc = 0.f;
  for (int dy = 0; dy < bs; ++dy) {
    const float* a = src + dy * 16;
    float s;
    if (bs == 16) {
      float r[8];
      #pragma unroll
      for (int j = 0; j < 8; ++j) r[j] = a[j] + a[8 + j];
      s = ((r[0] + r[1]) + (r[2] + r[3])) + ((r[4] + r[5]) + (r[6] + r[7]));
    } else if (bs == 8) {
      s = ((a[0] + a[1]) + (a[2] + a[3])) + ((a[4] + a[5]) + (a[6] + a[7]));
    } else if (bs == 4) {
      s = ((a[0] + a[1]) + a[2]) + a[3];
    } else {
      s = a[0] + a[1];
    }
    acc = acc + s;
  }
  zd[i] = acc * (1.f / (bs * bs));
}

// pack z -> bf16 [vec][c] + transposed f32 [vec][c] + zsq. numVec mult of 256.
__global__ void k_zpack(const float* __restrict__ zsrc, int pnpn,
                        u16* __restrict__ zhi, float* __restrict__ zt32,
                        float* __restrict__ zsq32) {
  int vec = blockIdx.x * 256 + threadIdx.x;
  int b = vec / pnpn, p = vec - b * pnpn;
  const float* zp = zsrc + (size_t)b * 64 * pnpn + p;
  u16* zo = zhi + (size_t)vec * 64;
  float* zt = zt32 + (size_t)vec * 64;
  double s = 0.0;
  #pragma unroll 8
  for (int c = 0; c < 64; ++c) {
    float v = zp[(size_t)c * pnpn];
    s = fma((double)v, (double)v, s);
    zo[c] = f2bf(v);
    zt[c] = v;
  }
  zsq32[vec] = (float)s;
}

// ---- argmin, small scales (exact path, proven) ----
__global__ __launch_bounds__(256, 4) void k_argmin(
    const float* __restrict__ zd, const float* __restrict__ emb,
    const float* __restrict__ wsq32,
    float* __restrict__ pd, int* __restrict__ pi,
    int numVec, int pnpn, int kchunk) {
#pragma clang fp contract(off)
  __shared__ __align__(16) float zt[32][68];
  __shared__ __align__(16) float et[64 * 64];
  __shared__ float ws_s[64];
  __shared__ float red_d[256];
  __shared__ int   red_i[256];
  int tid = threadIdx.x;
  int v0 = blockIdx.x * 32;
  int kbase = blockIdx.y * kchunk;

  for (int idx = tid; idx < 32 * 64; idx += 256) {
    int v = idx >> 6, c = idx & 63;
    int vi = v0 + v;
    float val = 0.f;
    if (vi < numVec) {
      int b = vi / pnpn, p = vi % pnpn;
      val = zd[(b * 64 + c) * pnpn + p];
    }
    zt[v][c] = val;
  }
  __syncthreads();

  const int v = tid & 31, kg = tid >> 5;
  float4 z4[16];
  #pragma unroll
  for (int i = 0; i < 16; ++i) z4[i] = *reinterpret_cast<float4*>(&zt[v][i * 4]);
  float zsq = 0.f;
  #pragma unroll
  for (int i = 0; i < 16; ++i)
    zsq += z4[i].x * z4[i].x + z4[i].y * z4[i].y + z4[i].z * z4[i].z + z4[i].w * z4[i].w;

  float bd = FLT_MAX; int bi = 0x7fffffff;
  for (int k0 = 0; k0 < kchunk; k0 += 64) {
    __syncthreads();
    {
      const float4* gsrc = reinterpret_cast<const float4*>(emb + (size_t)(kbase + k0) * 64);
      float4* ldst = reinterpret_cast<float4*>(et);
      #pragma unroll
      for (int idx = 0; idx < 4; ++idx)
        ldst[tid + idx * 256] = gsrc[tid + idx * 256];
    }
    if (tid < 64) ws_s[tid] = wsq32[kbase + k0 + tid];
    __syncthreads();
    #pragma unroll
    for (int j = 0; j < 8; ++j) {
      int kl = kg * 8 + j;
      const float4* e4 = reinterpret_cast<const float4*>(&et[kl * 64]);
      float acc = 0.f;
      #pragma unroll
      for (int i = 0; i < 16; ++i) {
        float4 e = e4[i];
        acc = __builtin_fmaf(z4[i].x, e.x, acc);
        acc = __builtin_fmaf(z4[i].y, e.y, acc);
        acc = __builtin_fmaf(z4[i].z, e.z, acc);
        acc = __builtin_fmaf(z4[i].w, e.w, acc);
      }
      float t1 = zsq + ws_s[kl];
      float d  = t1 - 2.0f * acc;
      if (d < bd) { bd = d; bi = kbase + k0 + kl; }
    }
  }
  red_d[tid] = bd; red_i[tid] = bi;
  __syncthreads();
  if (tid < 32) {
    float fb = red_d[tid]; int fi = red_i[tid];
    #pragma unroll
    for (int g = 1; g < 8; ++g) {
      float cd = red_d[g * 32 + tid]; int ci = red_i[g * 32 + tid];
      if (cd < fb || (cd == fb && ci < fi)) { fb = cd; fi = ci; }
    }
    int vi = v0 + tid;
    if (vi < numVec) {
      pd[blockIdx.y * numVec + vi] = fb;
      pi[blockIdx.y * numVec + vi] = fi;
    }
  }
}

// ---- argmin big scales: bf16 MFMA prefilter. grid (numVec/128, KS).
#define INS4(dd, ii)                                                   \
  { bool c0 = (dd) < q0, c1 = (dd) < q1, c2 = (dd) < q2, c3 = (dd) < q3; \
    q3 = c2 ? q2 : (c3 ? (dd) : q3); j3 = c2 ? j2 : (c3 ? (ii) : j3);  \
    q2 = c1 ? q1 : (c2 ? (dd) : q2); j2 = c1 ? j1 : (c2 ? (ii) : j2);  \
    q1 = c0 ? q0 : (c1 ? (dd) : q1); j1 = c0 ? j0 : (c1 ? (ii) : j1);  \
    q0 = c0 ? (dd) : q0;             j0 = c0 ? (ii) : j0; }

__global__ __launch_bounds__(256, 4) void k_argmin_mfma(
    const u16* __restrict__ zhi, const float* __restrict__ zsq32,
    const u16* __restrict__ ehi, const float* __restrict__ wsq32,
    float* __restrict__ cdp, int* __restrict__ cip,
    int numVec, int part) {
  __shared__ u16  es[2][64 * 72];
  __shared__ float wss[2][64];
  const int tid = threadIdx.x;
  const int wid = tid >> 6, lane = tid & 63;
  const int l15 = lane & 15, l4 = lane >> 4;
  const int vw = blockIdx.x * 128 + wid * 32;
  const int kbase = blockIdx.y * part;
  const int KSx = gridDim.y;

  bf16x8 za[2][2];
  f32x4 zq[2];
  #pragma unroll
  for (int s = 0; s < 2; ++s) {
    const u16* zp = zhi + (size_t)(vw + s * 16 + l15) * 64 + l4 * 8;
    za[s][0] = *reinterpret_cast<const bf16x8*>(zp);
    za[s][1] = *reinterpret_cast<const bf16x8*>(zp + 32);
    zq[s] = *reinterpret_cast<const f32x4*>(zsq32 + vw + s * 16 + l4 * 4);
  }

  float d1[2][4], d2[2][4], d3[2][4];
  int   i1[2][4], i2[2][4], i3[2][4];
  #pragma unroll
  for (int s = 0; s < 2; ++s)
    #pragma unroll
    for (int r = 0; r < 4; ++r) {
      d1[s][r] = FLT_MAX; d2[s][r] = FLT_MAX; d3[s][r] = FLT_MAX;
      i1[s][r] = 0x7fffffff; i2[s][r] = 0x7fffffff; i3[s][r] = 0x7fffffff;
    }

  const int NT = part >> 6;
  #define STAGE(buf, t)                                                      \
    { const u16* src = ehi + (size_t)(kbase + (t) * 64) * 64;                \
      int code = tid >> 2, seg = tid & 3;                                    \
      const bf16x8* s8 = reinterpret_cast<const bf16x8*>(src + code * 64 + seg * 16); \
      bf16x8 v0 = s8[0], v1 = s8[1];                                         \
      bf16x8* d8 = reinterpret_cast<bf16x8*>(&es[buf][code * 72 + seg * 16]);\
      d8[0] = v0; d8[1] = v1;                                                \
      if (tid < 64) wss[buf][tid] = wsq32[kbase + (t) * 64 + tid]; }

  STAGE(0, 0);
  __syncthreads();
  for (int t = 0; t < NT; ++t) {
    int cur = t & 1;
    if (t + 1 < NT) { STAGE(cur ^ 1, t + 1); }
    #pragma unroll
    for (int ct = 0; ct < 4; ++ct) {
      const u16* eb = &es[cur][(ct * 16 + l15) * 72 + l4 * 8];
      bf16x8 b0 = *reinterpret_cast<const bf16x8*>(eb);
      bf16x8 b1 = *reinterpret_cast<const bf16x8*>(eb + 32);
      float wl = wss[cur][ct * 16 + l15];
      int ki = kbase + t * 64 + ct * 16 + l15;
      #pragma unroll
      for (int s = 0; s < 2; ++s) {
        f32x4 acc = {0.f, 0.f, 0.f, 0.f};
        acc = __builtin_amdgcn_mfma_f32_16x16x32_bf16(za[s][0], b0, acc, 0, 0, 0);
        acc = __builtin_amdgcn_mfma_f32_16x16x32_bf16(za[s][1], b1, acc, 0, 0, 0);
        #pragma unroll
        for (int r = 0; r < 4; ++r) {
          float t1 = zq[s][r] + wl;
          float d  = fmaf(acc[r], -2.f, t1);
          bool c0 = d < d1[s][r], c1b = d < d2[s][r], c2b = d < d3[s][r];
          d3[s][r] = c1b ? d2[s][r] : (c2b ? d  : d3[s][r]);
          i3[s][r] = c1b ? i2[s][r] : (c2b ? ki : i3[s][r]);
          d2[s][r] = c0 ? d1[s][r] : (c1b ? d  : d2[s][r]);
          i2[s][r] = c0 ? i1[s][r] : (c1b ? ki : i2[s][r]);
          d1[s][r] = c0 ? d  : d1[s][r];
          i1[s][r] = c0 ? ki : i1[s][r];
        }
      }
    }
    __syncthreads();
  }

  // cross-column merge to part top-4; write CONTIGUOUS per vec: cand[vec][KSx*4]
  #pragma unroll
  for (int s = 0; s < 2; ++s)
    #pragma unroll
    for (int r = 0; r < 4; ++r) {
      float q0 = d1[s][r], q1 = d2[s][r], q2 = d3[s][r], q3 = FLT_MAX;
      int   j0 = i1[s][r], j1 = i2[s][r], j2 = i3[s][r], j3 = 0x7fffffff;
      #pragma unroll
      for (int m = 1; m < 16; m <<= 1) {
        float p0 = __shfl_xor(q0, m), p1 = __shfl_xor(q1, m);
        float p2 = __shfl_xor(q2, m), p3 = __shfl_xor(q3, m);
        int   o0 = __shfl_xor(j0, m), o1 = __shfl_xor(j1, m);
        int   o2 = __shfl_xor(j2, m), o3 = __shfl_xor(j3, m);
        INS4(p0, o0); INS4(p1, o1); INS4(p2, o2); INS4(p3, o3);
      }
      if (l15 == 0) {
        int vec = vw + s * 16 + l4 * 4 + r;
        size_t base = ((size_t)vec * KSx + blockIdx.y) * 4;
        cdp[base + 0] = q0; cdp[base + 1] = q1; cdp[base + 2] = q2; cdp[base + 3] = q3;
        cip[base + 0] = j0; cip[base + 1] = j1; cip[base + 2] = j2; cip[base + 3] = j3;
      }
    }
}

// exact (numpy-f32-chain) rescore of in-band candidates. 64-thr blocks, z from
// zt32 (contiguous float4s -> parallel loads), cand contiguous per vec.
__global__ __launch_bounds__(64) void k_rescore(
    const float* __restrict__ cdp, const int* __restrict__ cip,
    const float* __restrict__ zt32, const float* __restrict__ emb,
    const float* __restrict__ wsq32, const float* __restrict__ zsq32,
    float* __restrict__ pd, int* __restrict__ pi,
    int numVec, int ksplit) {
#pragma clang fp contract(off)
  int vec = blockIdx.x * 64 + threadIdx.x;
  if (vec >= numVec) return;
  float zsq = zsq32[vec];
  int ncand = ksplit * 4;

  float4 z4[16];
  {
    const float4* zp = reinterpret_cast<const float4*>(zt32 + (size_t)vec * 64);
    #pragma unroll
    for (int i = 0; i < 16; ++i) z4[i] = zp[i];
  }

  const float4* cd4 = reinterpret_cast<const float4*>(cdp + (size_t)vec * ncand);
  float dmin = FLT_MAX;
  for (int e4i = 0; e4i < (ncand >> 2); ++e4i) {
    float4 v = cd4[e4i];
    dmin = fminf(dmin, fminf(fminf(v.x, v.y), fminf(v.z, v.w)));
  }
  float band = dmin + fmaf(sqrtf(zsq), 1.25e-5f, 1e-4f);

  const float* cdb = cdp + (size_t)vec * ncand;
  const int*   cib = cip + (size_t)vec * ncand;
  float bd = FLT_MAX; int bi = 0x7fffffff;
  for (int e = 0; e < ncand; ++e) {
    if (cdb[e] > band) continue;
    int ki = cib[e];
    const float4* er = reinterpret_cast<const float4*>(emb + (size_t)ki * 64);
    float acc = 0.f;
    #pragma unroll
    for (int i = 0; i < 16; ++i) {
      float4 e4 = er[i];
      acc = __builtin_fmaf(z4[i].x, e4.x, acc);
      acc = __builtin_fmaf(z4[i].y, e4.y, acc);
      acc = __builtin_fmaf(z4[i].z, e4.z, acc);
      acc = __builtin_fmaf(z4[i].w, e4.w, acc);
    }
    float t1 = zsq + wsq32[ki];
    float d  = t1 - 2.0f * acc;
    if (d < bd || (d == bd && ki < bi)) { bd = d; bi = ki; }
  }
  pd[vec] = 0.f;
  pi[vec] = bi;
}

// ---- fused ksplit-reduce + cubic upsample ----
__global__ __launch_bounds__(256) void k_up(
    const float* __restrict__ pd, const int* __restrict__ pi,
    const float* __restrict__ emb, float* __restrict__ hup,
    int pn, int ksplit) {
  __shared__ float td[256];
  __shared__ int   ti[256];
  __shared__ int   tok_s[256];
  __shared__ float wsh[16][4];
  __shared__ int   i0sh[16];

  int t = threadIdx.x;
  int i = blockIdx.x * 256 + t;
  int p = i & 255; int c = (i >> 8) & 63; int b = i >> 14;
  int P = pn * pn;
  int numVec = BB * P;
  int R = 256 / P;
  int v = t % P, sg = t / P;

  float bd = FLT_MAX; int bi = 0x7fffffff;
  for (int s = sg; s < ksplit; s += R) {
    float cd = pd[s * numVec + b * P + v]; int ci = pi[s * numVec + b * P + v];
    if (cd < bd || (cd == bd && ci < bi)) { bd = cd; bi = ci; }
  }
  td[t] = bd; ti[t] = bi;
  __syncthreads();
  for (int r = R >> 1; r >= 1; r >>= 1) {
    if (sg < r) {
      float cd = td[t + r * P]; int ci = ti[t + r * P];
      if (cd < td[t] || (cd == td[t] && ci < ti[t])) { td[t] = cd; ti[t] = ci; }
    }
    __syncthreads();
  }
  if (t < P) tok_s[t] = ti[t];
  if (pn < 16 && t < 16) {
    double s = (t + 0.5) * ((double)pn / 16.0) - 0.5;
    int i0 = (int)floor(s) - 1;
    int hi = pn - 4; if (hi < 0) hi = 0;
    if (i0 < 0) i0 = 0; if (i0 > hi) i0 = hi;
    double wv[4]; double sum = 0.0;
    #pragma unroll
    for (int qq = 0; qq < 4; ++qq) {
      int ii = i0 + qq;
      double w = 0.0;
      if (ii < pn) {
        double xx = fabs(s - (double)ii);
        if (xx < 1.0)       w = ((1.5 * xx - 2.5) * xx) * xx + 1.0;
        else if (xx < 2.0)  w = ((-0.5 * xx + 2.5) * xx - 4.0) * xx + 2.0;
      }
      wv[qq] = w; sum += w;
    }
    i0sh[t] = i0;
    #pragma unroll
    for (int qq = 0; qq < 4; ++qq) wsh[t][qq] = (float)(wv[qq] / sum);
  }
  __syncthreads();

  if (pn == 16) { hup[i] = emb[(size_t)tok_s[p] * 64 + c]; return; }

  int y = p >> 4, x = p & 15;
  int iy0 = i0sh[y], ix0 = i0sh[x];
  float acc = 0.f;
  #pragma unroll
  for (int ty = 0; ty < 4; ++ty) {
    float wy = wsh[y][ty];
    int iy = iy0 + ty; if (iy > pn - 1) iy = pn - 1;
    float tmp = 0.f;
    #pragma unroll
    for (int tx = 0; tx < 4; ++tx) {
      float wx = wsh[x][tx];
      int ix = ix0 + tx; if (ix > pn - 1) ix = pn - 1;
      tmp += wx * emb[(size_t)tok_s[iy * pn + ix] * 64 + c];
    }
    acc += wy * tmp;
  }
  hup[i] = acc;
}

// ---- conv (round-8 proven version) ----
__global__ __launch_bounds__(256) void k_conv(
    const float* __restrict__ hup, const float* __restrict__ w,
    const float* __restrict__ bias, float* __restrict__ out, float* __restrict__ zr) {
  __shared__ __align__(16) float ins[16][18 * 18];
  __shared__ __align__(16) float wsh[8 * 64 * 12];
  int tid = threadIdx.x;
  int b = blockIdx.x;
  int ocb = blockIdx.y;

  for (int idx = tid; idx < 16 * 324; idx += 256)
    (&ins[0][0])[idx] = 0.f;
  for (int idx = tid; idx < 8 * 64 * 9; idx += 256) {
    int ocic = idx / 9, t = idx - ocic * 9;
    wsh[ocic * 12 + t] = w[(size_t)ocb * 8 * 64 * 9 + idx];
  }

  const int wid = tid >> 6, lane = tid & 63;
  const int ocg = wid >> 1;
  const int ph = (wid & 1) * 64 + lane;
  const int x = ph & 15, y2 = ph >> 4;

  float acc[4][2];
  #pragma unroll
  for (int j = 0; j < 4; ++j) {
    float bv = bias[ocb * 8 + ocg * 4 + j];
    acc[j][0] = bv; acc[j][1] = bv;
  }

  const float* hb = hup + (size_t)b * 64 * NPIX;
  float sreg[16];
  #pragma unroll
  for (int r = 0; r < 16; ++r) sreg[r] = hb[r * 256 + tid];

  for (int cc = 0; cc < 4; ++cc) {
    __syncthreads();
    #pragma unroll
    for (int r = 0; r < 16; ++r) {
      int idx = r * 256 + tid;
      int icl = idx >> 8, p = idx & 255;
      ins[icl][((p >> 4) + 1) * 18 + (p & 15) + 1] = sreg[r];
    }
    __syncthreads();
    if (cc < 3) {
      #pragma unroll
      for (int r = 0; r < 16; ++r) sreg[r] = hb[(cc + 1) * 4096 + r * 256 + tid];
    }

    #pragma unroll 2
    for (int icl = 0; icl < 16; ++icl) {
      float vt[4][3];
      const float* ip = &ins[icl][y2 * 2 * 18 + x];
      #pragma unroll
      for (int r = 0; r < 4; ++r)
        #pragma unroll
        for (int cxx = 0; cxx < 3; ++cxx)
          vt[r][cxx] = ip[r * 18 + cxx];

      int ic = cc * 16 + icl;
      #pragma unroll
      for (int j = 0; j < 4; ++j) {
        const float* wp = &wsh[((ocg * 4 + j) * 64 + ic) * 12];
        float4 wa = *reinterpret_cast<const float4*>(wp);
        float4 wb = *reinterpret_cast<const float4*>(wp + 4);
        float w8 = wp[8];
        float wv[9] = {wa.x, wa.y, wa.z, wa.w, wb.x, wb.y, wb.z, wb.w, w8};
        float a0 = acc[j][0], a1 = acc[j][1];
        #pragma unroll
        for (int dy = 0; dy < 3; ++dy)
          #pragma unroll
          for (int dx = 0; dx < 3; ++dx) {
            float wt = wv[dy * 3 + dx];
            a0 = __builtin_fmaf(vt[dy][dx], wt, a0);
            a1 = __builtin_fmaf(vt[dy + 1][dx], wt, a1);
          }
        acc[j][0] = a0; acc[j][1] = a1;
      }
    }
  }

  #pragma unroll
  for (int j = 0; j < 4; ++j) {
    int oc = ocb * 8 + ocg * 4 + j;
    #pragma unroll
    for (int r = 0; r < 2; ++r) {
      size_t gi = ((size_t)b * 64 + oc) * NPIX + (y2 * 2 + r) * 16 + x;
      float h = hup[gi];
      float ho = 0.5f * h + 0.5f * acc[j][r];
      out[gi] += ho;
      zr[gi]  -= ho;
    }
  }
}

extern "C" void kernel_launch(void* const* d_in, const int* in_sizes, int n_in,
                              void* d_out, int out_size, void* d_ws, size_t ws_size,
                              hipStream_t stream) {
  const float* f    = (const float*)d_in[0];
  const float* emb  = (const float*)d_in[1];
  const float* phiw = (const float*)d_in[2];
  const float* phib = (const float*)d_in[3];
  float* out = (float*)d_out;

  float* ws  = (float*)d_ws;
  float* zr     = ws;                        // 524288
  float* zd     = ws + 524288;               // 524288
  float* hup    = ws + 1048576;              // 524288
  float* wsq32  = ws + 1572864;              // 8192
  float* pd     = ws + 1581056;              // 65536
  int*   pi     = (int*)(ws + 1646592);      // 65536
  u16*   zhi    = (u16*)(ws + 1712128);      // 524288 u16
  u16*   ehi    = (u16*)(ws + 1974272);      // 524288 u16
  float* cand_d = ws + 2236416;              // 262144
  int*   cand_i = (int*)(ws + 2498560);      // 262144
  float* zsq32  = ws + 2760704;              // 8192
  float* zt32   = ws + 2768896;              // 524288
  // total ~13.2 MB

  // PHI_IDX (numpy linspace argmin in doubles)
  double start = 1.0 / 3.0 / 4.0;
  double stop  = 1.0 - 1.0 / 3.0 / 4.0;
  double step  = (stop - start) / 3.0;
  double ticks[4] = { start, 1.0 * step + start, 2.0 * step + start, stop };
  int phi_idx[5];
  for (int si = 0; si < 5; ++si) {
    double xx = si / 4.0;
    int bj = 0; double bdd = fabs(ticks[0] - xx);
    for (int j = 1; j < 4; ++j) { double dd = fabs(ticks[j] - xx); if (dd < bdd) { bdd = dd; bj = j; } }
    phi_idx[si] = bj;
  }

  static const int MSarr[5] = {1, 2, 4, 8, 16};

  k_prep<<<NELEM / 256, 256, 0, stream>>>(f, zr, out, emb, wsq32, ehi);

  const int KS[5] = {128, 32, 16, 32, 8};   // si>=3: parts for MFMA path
  for (int si = 0; si < 5; ++si) {
    int pn = MSarr[si], pnpn = pn * pn, numVec = BB * pnpn;
    const float* zsrc;
    if (si < 4) {
      int n = BB * CC * pnpn;
      k_down<<<(n + 255) / 256, 256, 0, stream>>>(zr, zd, pn);
      zsrc = zd;
    } else {
      zsrc = zr;
    }
    int ksplit = KS[si];
    if (si >= 3) {
      int part = KK / ksplit;
      k_zpack<<<numVec / 256, 256, 0, stream>>>(zsrc, pnpn, zhi, zt32, zsq32);
      dim3 g(numVec / 128, ksplit);
      k_argmin_mfma<<<g, 256, 0, stream>>>(zhi, zsq32, ehi, wsq32,
                                           cand_d, cand_i, numVec, part);
      k_rescore<<<numVec / 64, 64, 0, stream>>>(cand_d, cand_i, zt32, emb,
                                                wsq32, zsq32, pd, pi,
                                                numVec, ksplit);
      k_up<<<NELEM / 256, 256, 0, stream>>>(pd, pi, emb, hup, pn, 1);
    } else {
      int kchunk = KK / ksplit;
      dim3 g((numVec + 31) / 32, ksplit);
      k_argmin<<<g, 256, 0, stream>>>(zsrc, emb, wsq32, pd, pi, numVec, pnpn, kchunk);
      k_up<<<NELEM / 256, 256, 0, stream>>>(pd, pi, emb, hup, pn, ksplit);
    }
    int pidx = phi_idx[si];
    k_conv<<<dim3(BB, 8), 256, 0, stream>>>(hup, phiw + pidx * 64 * 64 * 9,
                                            phib + pidx * 64, out, zr);
  }
}

// Round 11
// 344.759 us; speedup vs baseline: 1.5471x; 1.2007x over previous
//
#include <hip/hip_runtime.h>
#include <math.h>
#include <float.h>

#define BB 32
#define CC 64
#define KK 8192
#define NPIX 256
#define NELEM (BB*CC*NPIX)  // 524288

typedef unsigned short u16;
typedef __attribute__((ext_vector_type(8))) short bf16x8;
typedef __attribute__((ext_vector_type(4))) float f32x4;

__device__ __forceinline__ u16 f2bf(float v) {   // RNE f32->bf16
  unsigned u = __float_as_uint(v);
  return (u16)((u + 0x7FFFu + ((u >> 16) & 1u)) >> 16);
}

// init zr/out + wsq + ehi(bf16 pack of emb) in one launch
__global__ void k_prep(const float* __restrict__ f, float* __restrict__ zr,
                       float* __restrict__ out, const float* __restrict__ emb,
                       float* __restrict__ wsq32, u16* __restrict__ ehi) {
  int i = blockIdx.x * 256 + threadIdx.x;
  if (i < NELEM) { zr[i] = f[i]; out[i] = 0.f; ehi[i] = f2bf(emb[i]); }
  if (i < KK) {
    const float* row = emb + i * 64;
    double s = 0.0;
    #pragma unroll
    for (int c = 0; c < 64; ++c) s += (double)row[c] * (double)row[c];
    wsq32[i] = (float)s;   // same-binade f32: argmin-safe (scheme-free)
  }
}

// numpy-exact area mean (pairwise row sums, sequential dy, exact pow2 scale)
__global__ void k_down(const float* __restrict__ zr, float* __restrict__ zd, int pn) {
#pragma clang fp contract(off)
  int i = blockIdx.x * 256 + threadIdx.x;
  int pnpn = pn * pn;
  int n = BB * CC * pnpn;
  if (i >= n) return;
  int x = i % pn; int y = (i / pn) % pn; int bc = i / pnpn;
  int bs = 16 / pn;
  const float* src = zr + bc * NPIX + (y * bs) * 16 + x * bs;
  float acc = 0.f;
  for (int dy = 0; dy < bs; ++dy) {
    const float* a = src + dy * 16;
    float s;
    if (bs == 16) {
      float r[8];
      #pragma unroll
      for (int j = 0; j < 8; ++j) r[j] = a[j] + a[8 + j];
      s = ((r[0] + r[1]) + (r[2] + r[3])) + ((r[4] + r[5]) + (r[6] + r[7]));
    } else if (bs == 8) {
      s = ((a[0] + a[1]) + (a[2] + a[3])) + ((a[4] + a[5]) + (a[6] + a[7]));
    } else if (bs == 4) {
      s = ((a[0] + a[1]) + a[2]) + a[3];
    } else {
      s = a[0] + a[1];
    }
    acc = acc + s;
  }
  zd[i] = acc * (1.f / (bs * bs));
}

// pack z -> bf16 [vec][c] + transposed f32 [vec][c] + zsq. numVec mult of 256.
__global__ void k_zpack(const float* __restrict__ zsrc, int pnpn,
                        u16* __restrict__ zhi, float* __restrict__ zt32,
                        float* __restrict__ zsq32) {
  int vec = blockIdx.x * 256 + threadIdx.x;
  int b = vec / pnpn, p = vec - b * pnpn;
  const float* zp = zsrc + (size_t)b * 64 * pnpn + p;
  u16* zo = zhi + (size_t)vec * 64;
  float* zt = zt32 + (size_t)vec * 64;
  double s = 0.0;
  #pragma unroll 8
  for (int c = 0; c < 64; ++c) {
    float v = zp[(size_t)c * pnpn];
    s = fma((double)v, (double)v, s);
    zo[c] = f2bf(v);
    zt[c] = v;
  }
  zsq32[vec] = (float)s;
}

// ---- argmin, small scales (exact path, proven) ----
__global__ __launch_bounds__(256, 4) void k_argmin(
    const float* __restrict__ zd, const float* __restrict__ emb,
    const float* __restrict__ wsq32,
    float* __restrict__ pd, int* __restrict__ pi,
    int numVec, int pnpn, int kchunk) {
#pragma clang fp contract(off)
  __shared__ __align__(16) float zt[32][68];
  __shared__ __align__(16) float et[64 * 64];
  __shared__ float ws_s[64];
  __shared__ float red_d[256];
  __shared__ int   red_i[256];
  int tid = threadIdx.x;
  int v0 = blockIdx.x * 32;
  int kbase = blockIdx.y * kchunk;

  for (int idx = tid; idx < 32 * 64; idx += 256) {
    int v = idx >> 6, c = idx & 63;
    int vi = v0 + v;
    float val = 0.f;
    if (vi < numVec) {
      int b = vi / pnpn, p = vi % pnpn;
      val = zd[(b * 64 + c) * pnpn + p];
    }
    zt[v][c] = val;
  }
  __syncthreads();

  const int v = tid & 31, kg = tid >> 5;
  float4 z4[16];
  #pragma unroll
  for (int i = 0; i < 16; ++i) z4[i] = *reinterpret_cast<float4*>(&zt[v][i * 4]);
  float zsq = 0.f;
  #pragma unroll
  for (int i = 0; i < 16; ++i)
    zsq += z4[i].x * z4[i].x + z4[i].y * z4[i].y + z4[i].z * z4[i].z + z4[i].w * z4[i].w;

  float bd = FLT_MAX; int bi = 0x7fffffff;
  for (int k0 = 0; k0 < kchunk; k0 += 64) {
    __syncthreads();
    {
      const float4* gsrc = reinterpret_cast<const float4*>(emb + (size_t)(kbase + k0) * 64);
      float4* ldst = reinterpret_cast<float4*>(et);
      #pragma unroll
      for (int idx = 0; idx < 4; ++idx)
        ldst[tid + idx * 256] = gsrc[tid + idx * 256];
    }
    if (tid < 64) ws_s[tid] = wsq32[kbase + k0 + tid];
    __syncthreads();
    #pragma unroll
    for (int j = 0; j < 8; ++j) {
      int kl = kg * 8 + j;
      const float4* e4 = reinterpret_cast<const float4*>(&et[kl * 64]);
      float acc = 0.f;
      #pragma unroll
      for (int i = 0; i < 16; ++i) {
        float4 e = e4[i];
        acc = __builtin_fmaf(z4[i].x, e.x, acc);
        acc = __builtin_fmaf(z4[i].y, e.y, acc);
        acc = __builtin_fmaf(z4[i].z, e.z, acc);
        acc = __builtin_fmaf(z4[i].w, e.w, acc);
      }
      float t1 = zsq + ws_s[kl];
      float d  = t1 - 2.0f * acc;
      if (d < bd) { bd = d; bi = kbase + k0 + kl; }
    }
  }
  red_d[tid] = bd; red_i[tid] = bi;
  __syncthreads();
  if (tid < 32) {
    float fb = red_d[tid]; int fi = red_i[tid];
    #pragma unroll
    for (int g = 1; g < 8; ++g) {
      float cd = red_d[g * 32 + tid]; int ci = red_i[g * 32 + tid];
      if (cd < fb || (cd == fb && ci < fi)) { fb = cd; fi = ci; }
    }
    int vi = v0 + tid;
    if (vi < numVec) {
      pd[blockIdx.y * numVec + vi] = fb;
      pi[blockIdx.y * numVec + vi] = fi;
    }
  }
}

// ---- argmin big scales: bf16 MFMA prefilter. grid (numVec/128, KS).
#define INS4(dd, ii)                                                   \
  { bool c0 = (dd) < q0, c1 = (dd) < q1, c2 = (dd) < q2, c3 = (dd) < q3; \
    q3 = c2 ? q2 : (c3 ? (dd) : q3); j3 = c2 ? j2 : (c3 ? (ii) : j3);  \
    q2 = c1 ? q1 : (c2 ? (dd) : q2); j2 = c1 ? j1 : (c2 ? (ii) : j2);  \
    q1 = c0 ? q0 : (c1 ? (dd) : q1); j1 = c0 ? j0 : (c1 ? (ii) : j1);  \
    q0 = c0 ? (dd) : q0;             j0 = c0 ? (ii) : j0; }

__global__ __launch_bounds__(256, 4) void k_argmin_mfma(
    const u16* __restrict__ zhi, const float* __restrict__ zsq32,
    const u16* __restrict__ ehi, const float* __restrict__ wsq32,
    float* __restrict__ cdp, int* __restrict__ cip,
    int numVec, int part) {
  __shared__ u16  es[2][64 * 72];
  __shared__ float wss[2][64];
  const int tid = threadIdx.x;
  const int wid = tid >> 6, lane = tid & 63;
  const int l15 = lane & 15, l4 = lane >> 4;
  const int vw = blockIdx.x * 128 + wid * 32;
  const int kbase = blockIdx.y * part;
  const int KSx = gridDim.y;

  bf16x8 za[2][2];
  f32x4 zq[2];
  #pragma unroll
  for (int s = 0; s < 2; ++s) {
    const u16* zp = zhi + (size_t)(vw + s * 16 + l15) * 64 + l4 * 8;
    za[s][0] = *reinterpret_cast<const bf16x8*>(zp);
    za[s][1] = *reinterpret_cast<const bf16x8*>(zp + 32);
    zq[s] = *reinterpret_cast<const f32x4*>(zsq32 + vw + s * 16 + l4 * 4);
  }

  float d1[2][4], d2[2][4], d3[2][4];
  int   i1[2][4], i2[2][4], i3[2][4];
  #pragma unroll
  for (int s = 0; s < 2; ++s)
    #pragma unroll
    for (int r = 0; r < 4; ++r) {
      d1[s][r] = FLT_MAX; d2[s][r] = FLT_MAX; d3[s][r] = FLT_MAX;
      i1[s][r] = 0x7fffffff; i2[s][r] = 0x7fffffff; i3[s][r] = 0x7fffffff;
    }

  const int NT = part >> 6;
  #define STAGE(buf, t)                                                      \
    { const u16* src = ehi + (size_t)(kbase + (t) * 64) * 64;                \
      int code = tid >> 2, seg = tid & 3;                                    \
      const bf16x8* s8 = reinterpret_cast<const bf16x8*>(src + code * 64 + seg * 16); \
      bf16x8 v0 = s8[0], v1 = s8[1];                                         \
      bf16x8* d8 = reinterpret_cast<bf16x8*>(&es[buf][code * 72 + seg * 16]);\
      d8[0] = v0; d8[1] = v1;                                                \
      if (tid < 64) wss[buf][tid] = wsq32[kbase + (t) * 64 + tid]; }

  STAGE(0, 0);
  __syncthreads();
  for (int t = 0; t < NT; ++t) {
    int cur = t & 1;
    if (t + 1 < NT) { STAGE(cur ^ 1, t + 1); }
    #pragma unroll
    for (int ct = 0; ct < 4; ++ct) {
      const u16* eb = &es[cur][(ct * 16 + l15) * 72 + l4 * 8];
      bf16x8 b0 = *reinterpret_cast<const bf16x8*>(eb);
      bf16x8 b1 = *reinterpret_cast<const bf16x8*>(eb + 32);
      float wl = wss[cur][ct * 16 + l15];
      int ki = kbase + t * 64 + ct * 16 + l15;
      #pragma unroll
      for (int s = 0; s < 2; ++s) {
        f32x4 acc = {0.f, 0.f, 0.f, 0.f};
        acc = __builtin_amdgcn_mfma_f32_16x16x32_bf16(za[s][0], b0, acc, 0, 0, 0);
        acc = __builtin_amdgcn_mfma_f32_16x16x32_bf16(za[s][1], b1, acc, 0, 0, 0);
        #pragma unroll
        for (int r = 0; r < 4; ++r) {
          float t1 = zq[s][r] + wl;
          float d  = fmaf(acc[r], -2.f, t1);
          bool c0 = d < d1[s][r], c1b = d < d2[s][r], c2b = d < d3[s][r];
          d3[s][r] = c1b ? d2[s][r] : (c2b ? d  : d3[s][r]);
          i3[s][r] = c1b ? i2[s][r] : (c2b ? ki : i3[s][r]);
          d2[s][r] = c0 ? d1[s][r] : (c1b ? d  : d2[s][r]);
          i2[s][r] = c0 ? i1[s][r] : (c1b ? ki : i2[s][r]);
          d1[s][r] = c0 ? d  : d1[s][r];
          i1[s][r] = c0 ? ki : i1[s][r];
        }
      }
    }
    __syncthreads();
  }

  // cross-column merge to part top-4; write CONTIGUOUS per vec: cand[vec][KSx*4]
  #pragma unroll
  for (int s = 0; s < 2; ++s)
    #pragma unroll
    for (int r = 0; r < 4; ++r) {
      float q0 = d1[s][r], q1 = d2[s][r], q2 = d3[s][r], q3 = FLT_MAX;
      int   j0 = i1[s][r], j1 = i2[s][r], j2 = i3[s][r], j3 = 0x7fffffff;
      #pragma unroll
      for (int m = 1; m < 16; m <<= 1) {
        float p0 = __shfl_xor(q0, m), p1 = __shfl_xor(q1, m);
        float p2 = __shfl_xor(q2, m), p3 = __shfl_xor(q3, m);
        int   o0 = __shfl_xor(j0, m), o1 = __shfl_xor(j1, m);
        int   o2 = __shfl_xor(j2, m), o3 = __shfl_xor(j3, m);
        INS4(p0, o0); INS4(p1, o1); INS4(p2, o2); INS4(p3, o3);
      }
      if (l15 == 0) {
        int vec = vw + s * 16 + l4 * 4 + r;
        size_t base = ((size_t)vec * KSx + blockIdx.y) * 4;
        cdp[base + 0] = q0; cdp[base + 1] = q1; cdp[base + 2] = q2; cdp[base + 3] = q3;
        cip[base + 0] = j0; cip[base + 1] = j1; cip[base + 2] = j2; cip[base + 3] = j3;
      }
    }
}

// exact rescore: wave-per-vector, lane-per-candidate. ncand <= 64.
// grid numVec/4, 256 thr = 4 waves.
__global__ __launch_bounds__(256) void k_rescore(
    const float* __restrict__ cdp, const int* __restrict__ cip,
    const float* __restrict__ zt32, const float* __restrict__ emb,
    const float* __restrict__ wsq32, const float* __restrict__ zsq32,
    float* __restrict__ pd, int* __restrict__ pi,
    int numVec, int ncand) {
#pragma clang fp contract(off)
  __shared__ float zsh[4][64];
  int tid = threadIdx.x;
  int wid = tid >> 6, lane = tid & 63;
  int v0 = blockIdx.x * 4;
  zsh[wid][lane] = zt32[(size_t)v0 * 64 + tid];   // 4 vecs x 64, coalesced
  __syncthreads();

  int vec = v0 + wid;
  float zsq = zsq32[vec];
  float dv = FLT_MAX; int ki = 0x7fffffff;
  if (lane < ncand) {
    dv = cdp[(size_t)vec * ncand + lane];   // coalesced
    ki = cip[(size_t)vec * ncand + lane];
  }
  float dmin = dv;
  #pragma unroll
  for (int m = 1; m < 64; m <<= 1) dmin = fminf(dmin, __shfl_xor(dmin, m, 64));
  float band = dmin + fmaf(sqrtf(zsq), 1.25e-5f, 1e-4f);

  float d = FLT_MAX; int bi = 0x7fffffff;
  if (dv <= band) {
    const float4* er = reinterpret_cast<const float4*>(emb + (size_t)ki * 64);
    float4 e4[16];
    #pragma unroll
    for (int i = 0; i < 16; ++i) e4[i] = er[i];   // 16 independent loads
    const float* zw = zsh[wid];
    float acc = 0.f;
    #pragma unroll
    for (int i = 0; i < 16; ++i) {                // exact ascending-c chain
      acc = __builtin_fmaf(zw[4 * i + 0], e4[i].x, acc);
      acc = __builtin_fmaf(zw[4 * i + 1], e4[i].y, acc);
      acc = __builtin_fmaf(zw[4 * i + 2], e4[i].z, acc);
      acc = __builtin_fmaf(zw[4 * i + 3], e4[i].w, acc);
    }
    float t1 = zsq + wsq32[ki];
    d = t1 - 2.0f * acc;
    bi = ki;
  }
  #pragma unroll
  for (int m = 1; m < 64; m <<= 1) {
    float od = __shfl_xor(d, m, 64);
    int   oi = __shfl_xor(bi, m, 64);
    if (od < d || (od == d && oi < bi)) { d = od; bi = oi; }
  }
  if (lane == 0) { pd[vec] = 0.f; pi[vec] = bi; }
}

// ---- fused ksplit-reduce + cubic upsample ----
__global__ __launch_bounds__(256) void k_up(
    const float* __restrict__ pd, const int* __restrict__ pi,
    const float* __restrict__ emb, float* __restrict__ hup,
    int pn, int ksplit) {
  __shared__ float td[256];
  __shared__ int   ti[256];
  __shared__ int   tok_s[256];
  __shared__ float wsh[16][4];
  __shared__ int   i0sh[16];

  int t = threadIdx.x;
  int i = blockIdx.x * 256 + t;
  int p = i & 255; int c = (i >> 8) & 63; int b = i >> 14;
  int P = pn * pn;
  int numVec = BB * P;
  int R = 256 / P;
  int v = t % P, sg = t / P;

  float bd = FLT_MAX; int bi = 0x7fffffff;
  for (int s = sg; s < ksplit; s += R) {
    float cd = pd[s * numVec + b * P + v]; int ci = pi[s * numVec + b * P + v];
    if (cd < bd || (cd == bd && ci < bi)) { bd = cd; bi = ci; }
  }
  td[t] = bd; ti[t] = bi;
  __syncthreads();
  for (int r = R >> 1; r >= 1; r >>= 1) {
    if (sg < r) {
      float cd = td[t + r * P]; int ci = ti[t + r * P];
      if (cd < td[t] || (cd == td[t] && ci < ti[t])) { td[t] = cd; ti[t] = ci; }
    }
    __syncthreads();
  }
  if (t < P) tok_s[t] = ti[t];
  if (pn < 16 && t < 16) {
    double s = (t + 0.5) * ((double)pn / 16.0) - 0.5;
    int i0 = (int)floor(s) - 1;
    int hi = pn - 4; if (hi < 0) hi = 0;
    if (i0 < 0) i0 = 0; if (i0 > hi) i0 = hi;
    double wv[4]; double sum = 0.0;
    #pragma unroll
    for (int qq = 0; qq < 4; ++qq) {
      int ii = i0 + qq;
      double w = 0.0;
      if (ii < pn) {
        double xx = fabs(s - (double)ii);
        if (xx < 1.0)       w = ((1.5 * xx - 2.5) * xx) * xx + 1.0;
        else if (xx < 2.0)  w = ((-0.5 * xx + 2.5) * xx - 4.0) * xx + 2.0;
      }
      wv[qq] = w; sum += w;
    }
    i0sh[t] = i0;
    #pragma unroll
    for (int qq = 0; qq < 4; ++qq) wsh[t][qq] = (float)(wv[qq] / sum);
  }
  __syncthreads();

  if (pn == 16) { hup[i] = emb[(size_t)tok_s[p] * 64 + c]; return; }

  int y = p >> 4, x = p & 15;
  int iy0 = i0sh[y], ix0 = i0sh[x];
  float acc = 0.f;
  #pragma unroll
  for (int ty = 0; ty < 4; ++ty) {
    float wy = wsh[y][ty];
    int iy = iy0 + ty; if (iy > pn - 1) iy = pn - 1;
    float tmp = 0.f;
    #pragma unroll
    for (int tx = 0; tx < 4; ++tx) {
      float wx = wsh[x][tx];
      int ix = ix0 + tx; if (ix > pn - 1) ix = pn - 1;
      tmp += wx * emb[(size_t)tok_s[iy * pn + ix] * 64 + c];
    }
    acc += wy * tmp;
  }
  hup[i] = acc;
}

// ---- conv (round-8 proven version) ----
__global__ __launch_bounds__(256) void k_conv(
    const float* __restrict__ hup, const float* __restrict__ w,
    const float* __restrict__ bias, float* __restrict__ out, float* __restrict__ zr) {
  __shared__ __align__(16) float ins[16][18 * 18];
  __shared__ __align__(16) float wsh[8 * 64 * 12];
  int tid = threadIdx.x;
  int b = blockIdx.x;
  int ocb = blockIdx.y;

  for (int idx = tid; idx < 16 * 324; idx += 256)
    (&ins[0][0])[idx] = 0.f;
  for (int idx = tid; idx < 8 * 64 * 9; idx += 256) {
    int ocic = idx / 9, t = idx - ocic * 9;
    wsh[ocic * 12 + t] = w[(size_t)ocb * 8 * 64 * 9 + idx];
  }

  const int wid = tid >> 6, lane = tid & 63;
  const int ocg = wid >> 1;
  const int ph = (wid & 1) * 64 + lane;
  const int x = ph & 15, y2 = ph >> 4;

  float acc[4][2];
  #pragma unroll
  for (int j = 0; j < 4; ++j) {
    float bv = bias[ocb * 8 + ocg * 4 + j];
    acc[j][0] = bv; acc[j][1] = bv;
  }

  const float* hb = hup + (size_t)b * 64 * NPIX;
  float sreg[16];
  #pragma unroll
  for (int r = 0; r < 16; ++r) sreg[r] = hb[r * 256 + tid];

  for (int cc = 0; cc < 4; ++cc) {
    __syncthreads();
    #pragma unroll
    for (int r = 0; r < 16; ++r) {
      int idx = r * 256 + tid;
      int icl = idx >> 8, p = idx & 255;
      ins[icl][((p >> 4) + 1) * 18 + (p & 15) + 1] = sreg[r];
    }
    __syncthreads();
    if (cc < 3) {
      #pragma unroll
      for (int r = 0; r < 16; ++r) sreg[r] = hb[(cc + 1) * 4096 + r * 256 + tid];
    }

    #pragma unroll 2
    for (int icl = 0; icl < 16; ++icl) {
      float vt[4][3];
      const float* ip = &ins[icl][y2 * 2 * 18 + x];
      #pragma unroll
      for (int r = 0; r < 4; ++r)
        #pragma unroll
        for (int cxx = 0; cxx < 3; ++cxx)
          vt[r][cxx] = ip[r * 18 + cxx];

      int ic = cc * 16 + icl;
      #pragma unroll
      for (int j = 0; j < 4; ++j) {
        const float* wp = &wsh[((ocg * 4 + j) * 64 + ic) * 12];
        float4 wa = *reinterpret_cast<const float4*>(wp);
        float4 wb = *reinterpret_cast<const float4*>(wp + 4);
        float w8 = wp[8];
        float wv[9] = {wa.x, wa.y, wa.z, wa.w, wb.x, wb.y, wb.z, wb.w, w8};
        float a0 = acc[j][0], a1 = acc[j][1];
        #pragma unroll
        for (int dy = 0; dy < 3; ++dy)
          #pragma unroll
          for (int dx = 0; dx < 3; ++dx) {
            float wt = wv[dy * 3 + dx];
            a0 = __builtin_fmaf(vt[dy][dx], wt, a0);
            a1 = __builtin_fmaf(vt[dy + 1][dx], wt, a1);
          }
        acc[j][0] = a0; acc[j][1] = a1;
      }
    }
  }

  #pragma unroll
  for (int j = 0; j < 4; ++j) {
    int oc = ocb * 8 + ocg * 4 + j;
    #pragma unroll
    for (int r = 0; r < 2; ++r) {
      size_t gi = ((size_t)b * 64 + oc) * NPIX + (y2 * 2 + r) * 16 + x;
      float h = hup[gi];
      float ho = 0.5f * h + 0.5f * acc[j][r];
      out[gi] += ho;
      zr[gi]  -= ho;
    }
  }
}

extern "C" void kernel_launch(void* const* d_in, const int* in_sizes, int n_in,
                              void* d_out, int out_size, void* d_ws, size_t ws_size,
                              hipStream_t stream) {
  const float* f    = (const float*)d_in[0];
  const float* emb  = (const float*)d_in[1];
  const float* phiw = (const float*)d_in[2];
  const float* phib = (const float*)d_in[3];
  float* out = (float*)d_out;

  float* ws  = (float*)d_ws;
  float* zr     = ws;                        // 524288
  float* zd     = ws + 524288;               // 524288
  float* hup    = ws + 1048576;              // 524288
  float* wsq32  = ws + 1572864;              // 8192
  float* pd     = ws + 1581056;              // 65536
  int*   pi     = (int*)(ws + 1646592);      // 65536
  u16*   zhi    = (u16*)(ws + 1712128);      // 524288 u16
  u16*   ehi    = (u16*)(ws + 1974272);      // 524288 u16
  float* cand_d = ws + 2236416;              // 262144
  int*   cand_i = (int*)(ws + 2498560);      // 262144
  float* zsq32  = ws + 2760704;              // 8192
  float* zt32   = ws + 2768896;              // 524288
  // total ~13.2 MB

  // PHI_IDX (numpy linspace argmin in doubles)
  double start = 1.0 / 3.0 / 4.0;
  double stop  = 1.0 - 1.0 / 3.0 / 4.0;
  double step  = (stop - start) / 3.0;
  double ticks[4] = { start, 1.0 * step + start, 2.0 * step + start, stop };
  int phi_idx[5];
  for (int si = 0; si < 5; ++si) {
    double xx = si / 4.0;
    int bj = 0; double bdd = fabs(ticks[0] - xx);
    for (int j = 1; j < 4; ++j) { double dd = fabs(ticks[j] - xx); if (dd < bdd) { bdd = dd; bj = j; } }
    phi_idx[si] = bj;
  }

  static const int MSarr[5] = {1, 2, 4, 8, 16};

  k_prep<<<NELEM / 256, 256, 0, stream>>>(f, zr, out, emb, wsq32, ehi);

  const int KS[5] = {128, 32, 16, 16, 8};   // si>=3: parts for MFMA path (ncand<=64)
  for (int si = 0; si < 5; ++si) {
    int pn = MSarr[si], pnpn = pn * pn, numVec = BB * pnpn;
    const float* zsrc;
    if (si < 4) {
      int n = BB * CC * pnpn;
      k_down<<<(n + 255) / 256, 256, 0, stream>>>(zr, zd, pn);
      zsrc = zd;
    } else {
      zsrc = zr;
    }
    int ksplit = KS[si];
    if (si >= 3) {
      int part = KK / ksplit;
      k_zpack<<<numVec / 256, 256, 0, stream>>>(zsrc, pnpn, zhi, zt32, zsq32);
      dim3 g(numVec / 128, ksplit);
      k_argmin_mfma<<<g, 256, 0, stream>>>(zhi, zsq32, ehi, wsq32,
                                           cand_d, cand_i, numVec, part);
      k_rescore<<<numVec / 4, 256, 0, stream>>>(cand_d, cand_i, zt32, emb,
                                                wsq32, zsq32, pd, pi,
                                                numVec, ksplit * 4);
      k_up<<<NELEM / 256, 256, 0, stream>>>(pd, pi, emb, hup, pn, 1);
    } else {
      int kchunk = KK / ksplit;
      dim3 g((numVec + 31) / 32, ksplit);
      k_argmin<<<g, 256, 0, stream>>>(zsrc, emb, wsq32, pd, pi, numVec, pnpn, kchunk);
      k_up<<<NELEM / 256, 256, 0, stream>>>(pd, pi, emb, hup, pn, ksplit);
    }
    int pidx = phi_idx[si];
    k_conv<<<dim3(BB, 8), 256, 0, stream>>>(hup, phiw + pidx * 64 * 64 * 9,
                                            phib + pidx * 64, out, zr);
  }
}

// Round 12
// 331.899 us; speedup vs baseline: 1.6070x; 1.0387x over previous
//
#include <hip/hip_runtime.h>
#include <math.h>
#include <float.h>

#define BB 32
#define CC 64
#define KK 8192
#define NPIX 256
#define NELEM (BB*CC*NPIX)  // 524288

typedef unsigned short u16;
typedef __attribute__((ext_vector_type(8))) short bf16x8;
typedef __attribute__((ext_vector_type(4))) float f32x4;

__device__ __forceinline__ u16 f2bf(float v) {   // RNE f32->bf16
  unsigned u = __float_as_uint(v);
  return (u16)((u + 0x7FFFu + ((u >> 16) & 1u)) >> 16);
}

// init zr/out + wsq + ehi(bf16 pack of emb) in one launch
__global__ void k_prep(const float* __restrict__ f, float* __restrict__ zr,
                       float* __restrict__ out, const float* __restrict__ emb,
                       float* __restrict__ wsq32, u16* __restrict__ ehi) {
  int i = blockIdx.x * 256 + threadIdx.x;
  if (i < NELEM) { zr[i] = f[i]; out[i] = 0.f; ehi[i] = f2bf(emb[i]); }
  if (i < KK) {
    const float* row = emb + i * 64;
    double s = 0.0;
    #pragma unroll
    for (int c = 0; c < 64; ++c) s += (double)row[c] * (double)row[c];
    wsq32[i] = (float)s;   // same-binade f32: argmin-safe (scheme-free)
  }
}

// numpy-exact area mean for small scales (pn<=4): feeds exact argmin path
__global__ void k_down(const float* __restrict__ zr, float* __restrict__ zd, int pn) {
#pragma clang fp contract(off)
  int i = blockIdx.x * 256 + threadIdx.x;
  int pnpn = pn * pn;
  int n = BB * CC * pnpn;
  if (i >= n) return;
  int x = i % pn; int y = (i / pn) % pn; int bc = i / pnpn;
  int bs = 16 / pn;
  const float* src = zr + bc * NPIX + (y * bs) * 16 + x * bs;
  float acc = 0.f;
  for (int dy = 0; dy < bs; ++dy) {
    const float* a = src + dy * 16;
    float s;
    if (bs == 16) {
      float r[8];
      #pragma unroll
      for (int j = 0; j < 8; ++j) r[j] = a[j] + a[8 + j];
      s = ((r[0] + r[1]) + (r[2] + r[3])) + ((r[4] + r[5]) + (r[6] + r[7]));
    } else if (bs == 8) {
      s = ((a[0] + a[1]) + (a[2] + a[3])) + ((a[4] + a[5]) + (a[6] + a[7]));
    } else if (bs == 4) {
      s = ((a[0] + a[1]) + a[2]) + a[3];
    } else {
      s = a[0] + a[1];
    }
    acc = acc + s;
  }
  zd[i] = acc * (1.f / (bs * bs));
}

// pack for MFMA path: lane-per-channel. bs=1 (si4, identity) or bs=2 (si3,
// fused numpy-exact 2x2 area mean). Writes zhi(bf16), zt32(f32), zsq32.
__global__ __launch_bounds__(256) void k_pack(
    const float* __restrict__ zr, int pn, int bs,
    u16* __restrict__ zhi, float* __restrict__ zt32, float* __restrict__ zsq32) {
#pragma clang fp contract(off)
  int tid = threadIdx.x;
  int lv = tid >> 6, c = tid & 63;
  int vec = blockIdx.x * 4 + lv;
  int pnpn = pn * pn;
  int b = vec / pnpn, p = vec % pnpn;
  int y = p / pn, x = p % pn;
  const float* src = zr + ((size_t)(b * 64 + c)) * 256 + (y * bs) * 16 + x * bs;
  float v;
  if (bs == 1) {
    v = src[0];
  } else {           // bs==2: ((a00+a01)) then + ((a10+a11)), * exact 0.25
    v = (src[0] + src[1]) + (src[16] + src[17]);
    v = v * 0.25f;
  }
  zhi[(size_t)vec * 64 + c] = f2bf(v);
  zt32[(size_t)vec * 64 + c] = v;
  double sq = (double)v * (double)v;
  #pragma unroll
  for (int m = 1; m < 64; m <<= 1)
    sq += __shfl_xor(sq, m, 64);        // f64 all-reduce: order-independent to 1e-15
  if (c == 0) zsq32[vec] = (float)sq;
}

// ---- argmin, small scales (exact path, proven) ----
__global__ __launch_bounds__(256, 4) void k_argmin(
    const float* __restrict__ zd, const float* __restrict__ emb,
    const float* __restrict__ wsq32,
    float* __restrict__ pd, int* __restrict__ pi,
    int numVec, int pnpn, int kchunk) {
#pragma clang fp contract(off)
  __shared__ __align__(16) float zt[32][68];
  __shared__ __align__(16) float et[64 * 64];
  __shared__ float ws_s[64];
  __shared__ float red_d[256];
  __shared__ int   red_i[256];
  int tid = threadIdx.x;
  int v0 = blockIdx.x * 32;
  int kbase = blockIdx.y * kchunk;

  for (int idx = tid; idx < 32 * 64; idx += 256) {
    int v = idx >> 6, c = idx & 63;
    int vi = v0 + v;
    float val = 0.f;
    if (vi < numVec) {
      int b = vi / pnpn, p = vi % pnpn;
      val = zd[(b * 64 + c) * pnpn + p];
    }
    zt[v][c] = val;
  }
  __syncthreads();

  const int v = tid & 31, kg = tid >> 5;
  float4 z4[16];
  #pragma unroll
  for (int i = 0; i < 16; ++i) z4[i] = *reinterpret_cast<float4*>(&zt[v][i * 4]);
  float zsq = 0.f;
  #pragma unroll
  for (int i = 0; i < 16; ++i)
    zsq += z4[i].x * z4[i].x + z4[i].y * z4[i].y + z4[i].z * z4[i].z + z4[i].w * z4[i].w;

  float bd = FLT_MAX; int bi = 0x7fffffff;
  for (int k0 = 0; k0 < kchunk; k0 += 64) {
    __syncthreads();
    {
      const float4* gsrc = reinterpret_cast<const float4*>(emb + (size_t)(kbase + k0) * 64);
      float4* ldst = reinterpret_cast<float4*>(et);
      #pragma unroll
      for (int idx = 0; idx < 4; ++idx)
        ldst[tid + idx * 256] = gsrc[tid + idx * 256];
    }
    if (tid < 64) ws_s[tid] = wsq32[kbase + k0 + tid];
    __syncthreads();
    #pragma unroll
    for (int j = 0; j < 8; ++j) {
      int kl = kg * 8 + j;
      const float4* e4 = reinterpret_cast<const float4*>(&et[kl * 64]);
      float acc = 0.f;
      #pragma unroll
      for (int i = 0; i < 16; ++i) {
        float4 e = e4[i];
        acc = __builtin_fmaf(z4[i].x, e.x, acc);
        acc = __builtin_fmaf(z4[i].y, e.y, acc);
        acc = __builtin_fmaf(z4[i].z, e.z, acc);
        acc = __builtin_fmaf(z4[i].w, e.w, acc);
      }
      float t1 = zsq + ws_s[kl];
      float d  = t1 - 2.0f * acc;
      if (d < bd) { bd = d; bi = kbase + k0 + kl; }
    }
  }
  red_d[tid] = bd; red_i[tid] = bi;
  __syncthreads();
  if (tid < 32) {
    float fb = red_d[tid]; int fi = red_i[tid];
    #pragma unroll
    for (int g = 1; g < 8; ++g) {
      float cd = red_d[g * 32 + tid]; int ci = red_i[g * 32 + tid];
      if (cd < fb || (cd == fb && ci < fi)) { fb = cd; fi = ci; }
    }
    int vi = v0 + tid;
    if (vi < numVec) {
      pd[blockIdx.y * numVec + vi] = fb;
      pi[blockIdx.y * numVec + vi] = fi;
    }
  }
}

// ---- argmin big scales: bf16 MFMA prefilter, top-2/lane (zq deferred).
#define INS4(dd, ii)                                                   \
  { bool c0 = (dd) < q0, c1 = (dd) < q1, c2 = (dd) < q2, c3 = (dd) < q3; \
    q3 = c2 ? q2 : (c3 ? (dd) : q3); j3 = c2 ? j2 : (c3 ? (ii) : j3);  \
    q2 = c1 ? q1 : (c2 ? (dd) : q2); j2 = c1 ? j1 : (c2 ? (ii) : j2);  \
    q1 = c0 ? q0 : (c1 ? (dd) : q1); j1 = c0 ? j0 : (c1 ? (ii) : j1);  \
    q0 = c0 ? (dd) : q0;             j0 = c0 ? (ii) : j0; }

__global__ __launch_bounds__(256, 4) void k_argmin_mfma(
    const u16* __restrict__ zhi, const float* __restrict__ zsq32,
    const u16* __restrict__ ehi, const float* __restrict__ wsq32,
    float* __restrict__ cdp, int* __restrict__ cip,
    int numVec, int part) {
  __shared__ u16  es[2][64 * 72];
  __shared__ float wss[2][64];
  const int tid = threadIdx.x;
  const int wid = tid >> 6, lane = tid & 63;
  const int l15 = lane & 15, l4 = lane >> 4;
  const int vw = blockIdx.x * 128 + wid * 32;
  const int kbase = blockIdx.y * part;
  const int KSx = gridDim.y;

  bf16x8 za[2][2];
  f32x4 zq[2];
  #pragma unroll
  for (int s = 0; s < 2; ++s) {
    const u16* zp = zhi + (size_t)(vw + s * 16 + l15) * 64 + l4 * 8;
    za[s][0] = *reinterpret_cast<const bf16x8*>(zp);
    za[s][1] = *reinterpret_cast<const bf16x8*>(zp + 32);
    zq[s] = *reinterpret_cast<const f32x4*>(zsq32 + vw + s * 16 + l4 * 4);
  }

  float d1[2][4], d2[2][4];
  int   i1[2][4], i2[2][4];
  #pragma unroll
  for (int s = 0; s < 2; ++s)
    #pragma unroll
    for (int r = 0; r < 4; ++r) {
      d1[s][r] = FLT_MAX; d2[s][r] = FLT_MAX;
      i1[s][r] = 0x7fffffff; i2[s][r] = 0x7fffffff;
    }

  const int NT = part >> 6;
  #define STAGE(buf, t)                                                      \
    { const u16* src = ehi + (size_t)(kbase + (t) * 64) * 64;                \
      int code = tid >> 2, seg = tid & 3;                                    \
      const bf16x8* s8 = reinterpret_cast<const bf16x8*>(src + code * 64 + seg * 16); \
      bf16x8 v0 = s8[0], v1 = s8[1];                                         \
      bf16x8* d8 = reinterpret_cast<bf16x8*>(&es[buf][code * 72 + seg * 16]);\
      d8[0] = v0; d8[1] = v1;                                                \
      if (tid < 64) wss[buf][tid] = wsq32[kbase + (t) * 64 + tid]; }

  STAGE(0, 0);
  __syncthreads();
  for (int t = 0; t < NT; ++t) {
    int cur = t & 1;
    if (t + 1 < NT) { STAGE(cur ^ 1, t + 1); }
    #pragma unroll
    for (int ct = 0; ct < 4; ++ct) {
      const u16* eb = &es[cur][(ct * 16 + l15) * 72 + l4 * 8];
      bf16x8 b0 = *reinterpret_cast<const bf16x8*>(eb);
      bf16x8 b1 = *reinterpret_cast<const bf16x8*>(eb + 32);
      float wl = wss[cur][ct * 16 + l15];
      int ki = kbase + t * 64 + ct * 16 + l15;
      #pragma unroll
      for (int s = 0; s < 2; ++s) {
        f32x4 acc = {0.f, 0.f, 0.f, 0.f};
        acc = __builtin_amdgcn_mfma_f32_16x16x32_bf16(za[s][0], b0, acc, 0, 0, 0);
        acc = __builtin_amdgcn_mfma_f32_16x16x32_bf16(za[s][1], b1, acc, 0, 0, 0);
        #pragma unroll
        for (int r = 0; r < 4; ++r) {
          // dd = wl - 2*dot  (zq is per-vector constant: deferred to writeout)
          float dd = __builtin_fmaf(acc[r], -2.f, wl);
          bool c0 = dd < d1[s][r];
          bool c1 = dd < d2[s][r];
          d2[s][r] = c0 ? d1[s][r] : (c1 ? dd : d2[s][r]);
          i2[s][r] = c0 ? i1[s][r] : (c1 ? ki : i2[s][r]);
          d1[s][r] = c0 ? dd : d1[s][r];
          i1[s][r] = c0 ? ki : i1[s][r];
        }
      }
    }
    __syncthreads();
  }

  // cross-column merge (same vec per l4-group): top-4 per part, add zq back
  #pragma unroll
  for (int s = 0; s < 2; ++s)
    #pragma unroll
    for (int r = 0; r < 4; ++r) {
      float q0 = d1[s][r], q1 = d2[s][r], q2 = FLT_MAX, q3 = FLT_MAX;
      int   j0 = i1[s][r], j1 = i2[s][r], j2 = 0x7fffffff, j3 = 0x7fffffff;
      #pragma unroll
      for (int m = 1; m < 16; m <<= 1) {
        float p0 = __shfl_xor(q0, m), p1 = __shfl_xor(q1, m);
        float p2 = __shfl_xor(q2, m), p3 = __shfl_xor(q3, m);
        int   o0 = __shfl_xor(j0, m), o1 = __shfl_xor(j1, m);
        int   o2 = __shfl_xor(j2, m), o3 = __shfl_xor(j3, m);
        INS4(p0, o0); INS4(p1, o1); INS4(p2, o2); INS4(p3, o3);
      }
      if (l15 == 0) {
        int vec = vw + s * 16 + l4 * 4 + r;
        float zqv = zq[s][r];
        size_t base = ((size_t)vec * KSx + blockIdx.y) * 4;
        cdp[base + 0] = zqv + q0; cdp[base + 1] = zqv + q1;
        cdp[base + 2] = zqv + q2; cdp[base + 3] = zqv + q3;
        cip[base + 0] = j0; cip[base + 1] = j1; cip[base + 2] = j2; cip[base + 3] = j3;
      }
    }
}

// exact rescore: wave-per-vector, lane-per-candidate (up to 2 slots, ncand<=128)
__global__ __launch_bounds__(256) void k_rescore(
    const float* __restrict__ cdp, const int* __restrict__ cip,
    const float* __restrict__ zt32, const float* __restrict__ emb,
    const float* __restrict__ wsq32, const float* __restrict__ zsq32,
    float* __restrict__ pd, int* __restrict__ pi,
    int numVec, int ncand) {
#pragma clang fp contract(off)
  __shared__ float zsh[4][64];
  int tid = threadIdx.x;
  int wid = tid >> 6, lane = tid & 63;
  int v0 = blockIdx.x * 4;
  zsh[wid][lane] = zt32[(size_t)v0 * 64 + tid];
  __syncthreads();

  int vec = v0 + wid;
  float zsq = zsq32[vec];
  const float* cdb = cdp + (size_t)vec * ncand;
  const int*   cib = cip + (size_t)vec * ncand;
  float dv0 = cdb[lane]; int ki0 = cib[lane];
  float dv1 = FLT_MAX;   int ki1 = 0x7fffffff;
  if (ncand > 64) { dv1 = cdb[lane + 64]; ki1 = cib[lane + 64]; }

  float dmin = fminf(dv0, dv1);
  #pragma unroll
  for (int m = 1; m < 64; m <<= 1) dmin = fminf(dmin, __shfl_xor(dmin, m, 64));
  float band = dmin + fmaf(sqrtf(zsq), 1.25e-5f, 1e-4f);

  const float* zw = zsh[wid];
  float d = FLT_MAX; int bi = 0x7fffffff;
  #pragma unroll
  for (int slot = 0; slot < 2; ++slot) {
    float dv = slot ? dv1 : dv0;
    int   kk = slot ? ki1 : ki0;
    if (dv <= band) {
      const float4* er = reinterpret_cast<const float4*>(emb + (size_t)kk * 64);
      float4 e4[16];
      #pragma unroll
      for (int i = 0; i < 16; ++i) e4[i] = er[i];
      float acc = 0.f;
      #pragma unroll
      for (int i = 0; i < 16; ++i) {               // exact ascending-c chain
        acc = __builtin_fmaf(zw[4 * i + 0], e4[i].x, acc);
        acc = __builtin_fmaf(zw[4 * i + 1], e4[i].y, acc);
        acc = __builtin_fmaf(zw[4 * i + 2], e4[i].z, acc);
        acc = __builtin_fmaf(zw[4 * i + 3], e4[i].w, acc);
      }
      float t1 = zsq + wsq32[kk];
      float dd = t1 - 2.0f * acc;
      if (dd < d || (dd == d && kk < bi)) { d = dd; bi = kk; }
    }
  }
  #pragma unroll
  for (int m = 1; m < 64; m <<= 1) {
    float od = __shfl_xor(d, m, 64);
    int   oi = __shfl_xor(bi, m, 64);
    if (od < d || (od == d && oi < bi)) { d = od; bi = oi; }
  }
  if (lane == 0) { pd[vec] = 0.f; pi[vec] = bi; }
}

// ---- fused ksplit-reduce + cubic upsample ----
__global__ __launch_bounds__(256) void k_up(
    const float* __restrict__ pd, const int* __restrict__ pi,
    const float* __restrict__ emb, float* __restrict__ hup,
    int pn, int ksplit) {
  __shared__ float td[256];
  __shared__ int   ti[256];
  __shared__ int   tok_s[256];
  __shared__ float wsh[16][4];
  __shared__ int   i0sh[16];

  int t = threadIdx.x;
  int i = blockIdx.x * 256 + t;
  int p = i & 255; int c = (i >> 8) & 63; int b = i >> 14;
  int P = pn * pn;
  int numVec = BB * P;
  int R = 256 / P;
  int v = t % P, sg = t / P;

  float bd = FLT_MAX; int bi = 0x7fffffff;
  for (int s = sg; s < ksplit; s += R) {
    float cd = pd[s * numVec + b * P + v]; int ci = pi[s * numVec + b * P + v];
    if (cd < bd || (cd == bd && ci < bi)) { bd = cd; bi = ci; }
  }
  td[t] = bd; ti[t] = bi;
  __syncthreads();
  for (int r = R >> 1; r >= 1; r >>= 1) {
    if (sg < r) {
      float cd = td[t + r * P]; int ci = ti[t + r * P];
      if (cd < td[t] || (cd == td[t] && ci < ti[t])) { td[t] = cd; ti[t] = ci; }
    }
    __syncthreads();
  }
  if (t < P) tok_s[t] = ti[t];
  if (pn < 16 && t < 16) {
    double s = (t + 0.5) * ((double)pn / 16.0) - 0.5;
    int i0 = (int)floor(s) - 1;
    int hi = pn - 4; if (hi < 0) hi = 0;
    if (i0 < 0) i0 = 0; if (i0 > hi) i0 = hi;
    double wv[4]; double sum = 0.0;
    #pragma unroll
    for (int qq = 0; qq < 4; ++qq) {
      int ii = i0 + qq;
      double w = 0.0;
      if (ii < pn) {
        double xx = fabs(s - (double)ii);
        if (xx < 1.0)       w = ((1.5 * xx - 2.5) * xx) * xx + 1.0;
        else if (xx < 2.0)  w = ((-0.5 * xx + 2.5) * xx - 4.0) * xx + 2.0;
      }
      wv[qq] = w; sum += w;
    }
    i0sh[t] = i0;
    #pragma unroll
    for (int qq = 0; qq < 4; ++qq) wsh[t][qq] = (float)(wv[qq] / sum);
  }
  __syncthreads();

  if (pn == 16) { hup[i] = emb[(size_t)tok_s[p] * 64 + c]; return; }

  int y = p >> 4, x = p & 15;
  int iy0 = i0sh[y], ix0 = i0sh[x];
  float acc = 0.f;
  #pragma unroll
  for (int ty = 0; ty < 4; ++ty) {
    float wy = wsh[y][ty];
    int iy = iy0 + ty; if (iy > pn - 1) iy = pn - 1;
    float tmp = 0.f;
    #pragma unroll
    for (int tx = 0; tx < 4; ++tx) {
      float wx = wsh[x][tx];
      int ix = ix0 + tx; if (ix > pn - 1) ix = pn - 1;
      tmp += wx * emb[(size_t)tok_s[iy * pn + ix] * 64 + c];
    }
    acc += wy * tmp;
  }
  hup[i] = acc;
}

// ---- conv (round-8 proven version) ----
__global__ __launch_bounds__(256) void k_conv(
    const float* __restrict__ hup, const float* __restrict__ w,
    const float* __restrict__ bias, float* __restrict__ out, float* __restrict__ zr) {
  __shared__ __align__(16) float ins[16][18 * 18];
  __shared__ __align__(16) float wsh[8 * 64 * 12];
  int tid = threadIdx.x;
  int b = blockIdx.x;
  int ocb = blockIdx.y;

  for (int idx = tid; idx < 16 * 324; idx += 256)
    (&ins[0][0])[idx] = 0.f;
  for (int idx = tid; idx < 8 * 64 * 9; idx += 256) {
    int ocic = idx / 9, t = idx - ocic * 9;
    wsh[ocic * 12 + t] = w[(size_t)ocb * 8 * 64 * 9 + idx];
  }

  const int wid = tid >> 6, lane = tid & 63;
  const int ocg = wid >> 1;
  const int ph = (wid & 1) * 64 + lane;
  const int x = ph & 15, y2 = ph >> 4;

  float acc[4][2];
  #pragma unroll
  for (int j = 0; j < 4; ++j) {
    float bv = bias[ocb * 8 + ocg * 4 + j];
    acc[j][0] = bv; acc[j][1] = bv;
  }

  const float* hb = hup + (size_t)b * 64 * NPIX;
  float sreg[16];
  #pragma unroll
  for (int r = 0; r < 16; ++r) sreg[r] = hb[r * 256 + tid];

  for (int cc = 0; cc < 4; ++cc) {
    __syncthreads();
    #pragma unroll
    for (int r = 0; r < 16; ++r) {
      int idx = r * 256 + tid;
      int icl = idx >> 8, p = idx & 255;
      ins[icl][((p >> 4) + 1) * 18 + (p & 15) + 1] = sreg[r];
    }
    __syncthreads();
    if (cc < 3) {
      #pragma unroll
      for (int r = 0; r < 16; ++r) sreg[r] = hb[(cc + 1) * 4096 + r * 256 + tid];
    }

    #pragma unroll 2
    for (int icl = 0; icl < 16; ++icl) {
      float vt[4][3];
      const float* ip = &ins[icl][y2 * 2 * 18 + x];
      #pragma unroll
      for (int r = 0; r < 4; ++r)
        #pragma unroll
        for (int cxx = 0; cxx < 3; ++cxx)
          vt[r][cxx] = ip[r * 18 + cxx];

      int ic = cc * 16 + icl;
      #pragma unroll
      for (int j = 0; j < 4; ++j) {
        const float* wp = &wsh[((ocg * 4 + j) * 64 + ic) * 12];
        float4 wa = *reinterpret_cast<const float4*>(wp);
        float4 wb = *reinterpret_cast<const float4*>(wp + 4);
        float w8 = wp[8];
        float wv[9] = {wa.x, wa.y, wa.z, wa.w, wb.x, wb.y, wb.z, wb.w, w8};
        float a0 = acc[j][0], a1 = acc[j][1];
        #pragma unroll
        for (int dy = 0; dy < 3; ++dy)
          #pragma unroll
          for (int dx = 0; dx < 3; ++dx) {
            float wt = wv[dy * 3 + dx];
            a0 = __builtin_fmaf(vt[dy][dx], wt, a0);
            a1 = __builtin_fmaf(vt[dy + 1][dx], wt, a1);
          }
        acc[j][0] = a0; acc[j][1] = a1;
      }
    }
  }

  #pragma unroll
  for (int j = 0; j < 4; ++j) {
    int oc = ocb * 8 + ocg * 4 + j;
    #pragma unroll
    for (int r = 0; r < 2; ++r) {
      size_t gi = ((size_t)b * 64 + oc) * NPIX + (y2 * 2 + r) * 16 + x;
      float h = hup[gi];
      float ho = 0.5f * h + 0.5f * acc[j][r];
      out[gi] += ho;
      zr[gi]  -= ho;
    }
  }
}

extern "C" void kernel_launch(void* const* d_in, const int* in_sizes, int n_in,
                              void* d_out, int out_size, void* d_ws, size_t ws_size,
                              hipStream_t stream) {
  const float* f    = (const float*)d_in[0];
  const float* emb  = (const float*)d_in[1];
  const float* phiw = (const float*)d_in[2];
  const float* phib = (const float*)d_in[3];
  float* out = (float*)d_out;

  float* ws  = (float*)d_ws;
  float* zr     = ws;                        // 524288
  float* zd     = ws + 524288;               // 32768 (si<=2 only: pn<=4)
  float* hup    = ws + 557056;               // 524288
  float* wsq32  = ws + 1081344;              // 8192
  float* pd     = ws + 1089536;              // 8192
  int*   pi     = (int*)(ws + 1097728);      // 8192
  u16*   zhi    = (u16*)(ws + 1105920);      // 524288 u16 = 262144 f
  u16*   ehi    = (u16*)(ws + 1368064);      // 524288 u16 = 262144 f
  float* cand_d = ws + 1630208;              // 524288
  int*   cand_i = (int*)(ws + 2154496);      // 524288
  float* zsq32  = ws + 2678784;              // 8192
  float* zt32   = ws + 2686976;              // 524288
  // end 3211264 floats = 12.85 MB

  // PHI_IDX (numpy linspace argmin in doubles)
  double start = 1.0 / 3.0 / 4.0;
  double stop  = 1.0 - 1.0 / 3.0 / 4.0;
  double step  = (stop - start) / 3.0;
  double ticks[4] = { start, 1.0 * step + start, 2.0 * step + start, stop };
  int phi_idx[5];
  for (int si = 0; si < 5; ++si) {
    double xx = si / 4.0;
    int bj = 0; double bdd = fabs(ticks[0] - xx);
    for (int j = 1; j < 4; ++j) { double dd = fabs(ticks[j] - xx); if (dd < bdd) { bdd = dd; bj = j; } }
    phi_idx[si] = bj;
  }

  static const int MSarr[5] = {1, 2, 4, 8, 16};

  k_prep<<<NELEM / 256, 256, 0, stream>>>(f, zr, out, emb, wsq32, ehi);

  // si<=2: exact-path ksplits; si>=3: MFMA parts (si3: ncand=128, si4: 64)
  const int KS[5] = {128, 32, 16, 32, 16};
  for (int si = 0; si < 5; ++si) {
    int pn = MSarr[si], pnpn = pn * pn, numVec = BB * pnpn;
    int ksplit = KS[si];
    if (si >= 3) {
      int bs = 16 / pn;                       // 2 (si3) or 1 (si4)
      int part = KK / ksplit;
      k_pack<<<numVec / 4, 256, 0, stream>>>(zr, pn, bs, zhi, zt32, zsq32);
      dim3 g(numVec / 128, ksplit);
      k_argmin_mfma<<<g, 256, 0, stream>>>(zhi, zsq32, ehi, wsq32,
                                           cand_d, cand_i, numVec, part);
      k_rescore<<<numVec / 4, 256, 0, stream>>>(cand_d, cand_i, zt32, emb,
                                                wsq32, zsq32, pd, pi,
                                                numVec, ksplit * 4);
      k_up<<<NELEM / 256, 256, 0, stream>>>(pd, pi, emb, hup, pn, 1);
    } else {
      int n = BB * CC * pnpn;
      k_down<<<(n + 255) / 256, 256, 0, stream>>>(zr, zd, pn);
      int kchunk = KK / ksplit;
      dim3 g((numVec + 31) / 32, ksplit);
      k_argmin<<<g, 256, 0, stream>>>(zd, emb, wsq32, pd, pi, numVec, pnpn, kchunk);
      k_up<<<NELEM / 256, 256, 0, stream>>>(pd, pi, emb, hup, pn, ksplit);
    }
    int pidx = phi_idx[si];
    k_conv<<<dim3(BB, 8), 256, 0, stream>>>(hup, phiw + pidx * 64 * 64 * 9,
                                            phib + pidx * 64, out, zr);
  }
}

// Round 13
// 326.036 us; speedup vs baseline: 1.6359x; 1.0180x over previous
//
#include <hip/hip_runtime.h>
#include <math.h>
#include <float.h>

#define BB 32
#define CC 64
#define KK 8192
#define NPIX 256
#define NELEM (BB*CC*NPIX)  // 524288

typedef unsigned short u16;
typedef __attribute__((ext_vector_type(8))) short bf16x8;
typedef __attribute__((ext_vector_type(4))) float f32x4;

__device__ __forceinline__ u16 f2bf(float v) {   // RNE f32->bf16
  unsigned u = __float_as_uint(v);
  return (u16)((u + 0x7FFFu + ((u >> 16) & 1u)) >> 16);
}

// init zr/out + wsq + ehi(bf16 pack of emb) in one launch
__global__ void k_prep(const float* __restrict__ f, float* __restrict__ zr,
                       float* __restrict__ out, const float* __restrict__ emb,
                       float* __restrict__ wsq32, u16* __restrict__ ehi) {
  int i = blockIdx.x * 256 + threadIdx.x;
  if (i < NELEM) { zr[i] = f[i]; out[i] = 0.f; ehi[i] = f2bf(emb[i]); }
  if (i < KK) {
    const float* row = emb + i * 64;
    double s = 0.0;
    #pragma unroll
    for (int c = 0; c < 64; ++c) s += (double)row[c] * (double)row[c];
    wsq32[i] = (float)s;   // same-binade f32: argmin-safe (scheme-free)
  }
}

// numpy-exact area mean for small scales (pn<=4): feeds exact argmin path
__global__ void k_down(const float* __restrict__ zr, float* __restrict__ zd, int pn) {
#pragma clang fp contract(off)
  int i = blockIdx.x * 256 + threadIdx.x;
  int pnpn = pn * pn;
  int n = BB * CC * pnpn;
  if (i >= n) return;
  int x = i % pn; int y = (i / pn) % pn; int bc = i / pnpn;
  int bs = 16 / pn;
  const float* src = zr + bc * NPIX + (y * bs) * 16 + x * bs;
  float acc = 0.f;
  for (int dy = 0; dy < bs; ++dy) {
    const float* a = src + dy * 16;
    float s;
    if (bs == 16) {
      float r[8];
      #pragma unroll
      for (int j = 0; j < 8; ++j) r[j] = a[j] + a[8 + j];
      s = ((r[0] + r[1]) + (r[2] + r[3])) + ((r[4] + r[5]) + (r[6] + r[7]));
    } else if (bs == 8) {
      s = ((a[0] + a[1]) + (a[2] + a[3])) + ((a[4] + a[5]) + (a[6] + a[7]));
    } else if (bs == 4) {
      s = ((a[0] + a[1]) + a[2]) + a[3];
    } else {
      s = a[0] + a[1];
    }
    acc = acc + s;
  }
  zd[i] = acc * (1.f / (bs * bs));
}

// pack for MFMA path: lane-per-channel. bs=1 (si4) or bs=2 (si3, fused
// numpy-exact 2x2 area mean). Writes zhi(bf16), zt32(f32), zsq32.
__global__ __launch_bounds__(256) void k_pack(
    const float* __restrict__ zr, int pn, int bs,
    u16* __restrict__ zhi, float* __restrict__ zt32, float* __restrict__ zsq32) {
#pragma clang fp contract(off)
  int tid = threadIdx.x;
  int lv = tid >> 6, c = tid & 63;
  int vec = blockIdx.x * 4 + lv;
  int pnpn = pn * pn;
  int b = vec / pnpn, p = vec % pnpn;
  int y = p / pn, x = p % pn;
  const float* src = zr + ((size_t)(b * 64 + c)) * 256 + (y * bs) * 16 + x * bs;
  float v;
  if (bs == 1) {
    v = src[0];
  } else {           // bs==2: (a00+a01) + (a10+a11), * exact 0.25
    v = (src[0] + src[1]) + (src[16] + src[17]);
    v = v * 0.25f;
  }
  zhi[(size_t)vec * 64 + c] = f2bf(v);
  zt32[(size_t)vec * 64 + c] = v;
  double sq = (double)v * (double)v;
  #pragma unroll
  for (int m = 1; m < 64; m <<= 1)
    sq += __shfl_xor(sq, m, 64);        // f64 all-reduce: order-independent to 1e-15
  if (c == 0) zsq32[vec] = (float)sq;
}

// ---- argmin, small scales (exact path, proven) ----
__global__ __launch_bounds__(256, 4) void k_argmin(
    const float* __restrict__ zd, const float* __restrict__ emb,
    const float* __restrict__ wsq32,
    float* __restrict__ pd, int* __restrict__ pi,
    int numVec, int pnpn, int kchunk) {
#pragma clang fp contract(off)
  __shared__ __align__(16) float zt[32][68];
  __shared__ __align__(16) float et[64 * 64];
  __shared__ float ws_s[64];
  __shared__ float red_d[256];
  __shared__ int   red_i[256];
  int tid = threadIdx.x;
  int v0 = blockIdx.x * 32;
  int kbase = blockIdx.y * kchunk;

  for (int idx = tid; idx < 32 * 64; idx += 256) {
    int v = idx >> 6, c = idx & 63;
    int vi = v0 + v;
    float val = 0.f;
    if (vi < numVec) {
      int b = vi / pnpn, p = vi % pnpn;
      val = zd[(b * 64 + c) * pnpn + p];
    }
    zt[v][c] = val;
  }
  __syncthreads();

  const int v = tid & 31, kg = tid >> 5;
  float4 z4[16];
  #pragma unroll
  for (int i = 0; i < 16; ++i) z4[i] = *reinterpret_cast<float4*>(&zt[v][i * 4]);
  float zsq = 0.f;
  #pragma unroll
  for (int i = 0; i < 16; ++i)
    zsq += z4[i].x * z4[i].x + z4[i].y * z4[i].y + z4[i].z * z4[i].z + z4[i].w * z4[i].w;

  float bd = FLT_MAX; int bi = 0x7fffffff;
  for (int k0 = 0; k0 < kchunk; k0 += 64) {
    __syncthreads();
    {
      const float4* gsrc = reinterpret_cast<const float4*>(emb + (size_t)(kbase + k0) * 64);
      float4* ldst = reinterpret_cast<float4*>(et);
      #pragma unroll
      for (int idx = 0; idx < 4; ++idx)
        ldst[tid + idx * 256] = gsrc[tid + idx * 256];
    }
    if (tid < 64) ws_s[tid] = wsq32[kbase + k0 + tid];
    __syncthreads();
    #pragma unroll
    for (int j = 0; j < 8; ++j) {
      int kl = kg * 8 + j;
      const float4* e4 = reinterpret_cast<const float4*>(&et[kl * 64]);
      float acc = 0.f;
      #pragma unroll
      for (int i = 0; i < 16; ++i) {
        float4 e = e4[i];
        acc = __builtin_fmaf(z4[i].x, e.x, acc);
        acc = __builtin_fmaf(z4[i].y, e.y, acc);
        acc = __builtin_fmaf(z4[i].z, e.z, acc);
        acc = __builtin_fmaf(z4[i].w, e.w, acc);
      }
      float t1 = zsq + ws_s[kl];
      float d  = t1 - 2.0f * acc;
      if (d < bd) { bd = d; bi = kbase + k0 + kl; }
    }
  }
  red_d[tid] = bd; red_i[tid] = bi;
  __syncthreads();
  if (tid < 32) {
    float fb = red_d[tid]; int fi = red_i[tid];
    #pragma unroll
    for (int g = 1; g < 8; ++g) {
      float cd = red_d[g * 32 + tid]; int ci = red_i[g * 32 + tid];
      if (cd < fb || (cd == fb && ci < fi)) { fb = cd; fi = ci; }
    }
    int vi = v0 + tid;
    if (vi < numVec) {
      pd[blockIdx.y * numVec + vi] = fb;
      pi[blockIdx.y * numVec + vi] = fi;
    }
  }
}

// ---- argmin big scales: bf16 MFMA prefilter with PACKED KEYS.
// key = (dd & 0xFFFFFF00) | id  (dd = wsq - 2*dot; zq deferred forever —
// per-vector constant doesn't affect per-vector ordering). id = code idx
// within 256-code part (8 bits). top-2/lane via min+med3, no index regs.
#define INSK(kk)                                                       \
  { bool c0 = (kk) < q0, c1 = (kk) < q1, c2 = (kk) < q2, c3 = (kk) < q3; \
    q3 = c2 ? q2 : (c3 ? (kk) : q3);                                   \
    q2 = c1 ? q1 : (c2 ? (kk) : q2);                                   \
    q1 = c0 ? q0 : (c1 ? (kk) : q1);                                   \
    q0 = c0 ? (kk) : q0; }

__global__ __launch_bounds__(256, 8) void k_argmin_mfma(
    const u16* __restrict__ zhi, const u16* __restrict__ ehi,
    const float* __restrict__ wsq32, float* __restrict__ cdp,
    int numVec, int part) {
  __shared__ u16  es[2][64 * 72];
  __shared__ float wss[2][64];
  const int tid = threadIdx.x;
  const int wid = tid >> 6, lane = tid & 63;
  const int l15 = lane & 15, l4 = lane >> 4;
  const int vw = blockIdx.x * 128 + wid * 32;
  const int kbase = blockIdx.y * part;
  const int KSx = gridDim.y;

  bf16x8 za[2][2];
  #pragma unroll
  for (int s = 0; s < 2; ++s) {
    const u16* zp = zhi + (size_t)(vw + s * 16 + l15) * 64 + l4 * 8;
    za[s][0] = *reinterpret_cast<const bf16x8*>(zp);
    za[s][1] = *reinterpret_cast<const bf16x8*>(zp + 32);
  }

  float d1[2][4], d2[2][4];
  #pragma unroll
  for (int s = 0; s < 2; ++s)
    #pragma unroll
    for (int r = 0; r < 4; ++r) { d1[s][r] = FLT_MAX; d2[s][r] = FLT_MAX; }

  const int NT = part >> 6;
  #define STAGE(buf, t)                                                      \
    { const u16* src = ehi + (size_t)(kbase + (t) * 64) * 64;                \
      int code = tid >> 2, seg = tid & 3;                                    \
      const bf16x8* s8 = reinterpret_cast<const bf16x8*>(src + code * 64 + seg * 16); \
      bf16x8 v0 = s8[0], v1 = s8[1];                                         \
      bf16x8* d8 = reinterpret_cast<bf16x8*>(&es[buf][code * 72 + seg * 16]);\
      d8[0] = v0; d8[1] = v1;                                                \
      if (tid < 64) wss[buf][tid] = wsq32[kbase + (t) * 64 + tid]; }

  STAGE(0, 0);
  __syncthreads();
  for (int t = 0; t < NT; ++t) {
    int cur = t & 1;
    if (t + 1 < NT) { STAGE(cur ^ 1, t + 1); }
    #pragma unroll
    for (int ct = 0; ct < 4; ++ct) {
      const u16* eb = &es[cur][(ct * 16 + l15) * 72 + l4 * 8];
      bf16x8 b0 = *reinterpret_cast<const bf16x8*>(eb);
      bf16x8 b1 = *reinterpret_cast<const bf16x8*>(eb + 32);
      float wl = wss[cur][ct * 16 + l15];
      unsigned idu = (unsigned)(t * 64 + ct * 16 + l15);   // < 256
      #pragma unroll
      for (int s = 0; s < 2; ++s) {
        f32x4 acc = {0.f, 0.f, 0.f, 0.f};
        acc = __builtin_amdgcn_mfma_f32_16x16x32_bf16(za[s][0], b0, acc, 0, 0, 0);
        acc = __builtin_amdgcn_mfma_f32_16x16x32_bf16(za[s][1], b1, acc, 0, 0, 0);
        #pragma unroll
        for (int r = 0; r < 4; ++r) {
          float dd = __builtin_fmaf(acc[r], -2.f, wl);
          float key = __uint_as_float((__float_as_uint(dd) & 0xFFFFFF00u) | idu);
          float o1 = d1[s][r];
          d2[s][r] = __builtin_amdgcn_fmed3f(o1, key, d2[s][r]);
          d1[s][r] = fminf(o1, key);
        }
      }
    }
    __syncthreads();
  }

  // cross-column merge (16 lanes of same vec): top-4 keys per part
  #pragma unroll
  for (int s = 0; s < 2; ++s)
    #pragma unroll
    for (int r = 0; r < 4; ++r) {
      float q0 = d1[s][r], q1 = d2[s][r], q2 = FLT_MAX, q3 = FLT_MAX;
      #pragma unroll
      for (int m = 1; m < 16; m <<= 1) {
        float p0 = __shfl_xor(q0, m), p1 = __shfl_xor(q1, m);
        float p2 = __shfl_xor(q2, m), p3 = __shfl_xor(q3, m);
        INSK(p0); INSK(p1); INSK(p2); INSK(p3);
      }
      if (l15 == 0) {
        int vec = vw + s * 16 + l4 * 4 + r;
        size_t base = ((size_t)vec * KSx + blockIdx.y) * 4;
        cdp[base + 0] = q0; cdp[base + 1] = q1;
        cdp[base + 2] = q2; cdp[base + 3] = q3;
      }
    }
}

// exact rescore: wave-per-vector, lane-per-candidate (2 slots, ncand=128).
// decodes code idx from packed key: ki = part*256 + (bits & 0xFF).
__global__ __launch_bounds__(256) void k_rescore(
    const float* __restrict__ cdp, const float* __restrict__ zt32,
    const float* __restrict__ emb, const float* __restrict__ wsq32,
    const float* __restrict__ zsq32,
    float* __restrict__ pd, int* __restrict__ pi,
    int numVec, int ncand) {
#pragma clang fp contract(off)
  __shared__ float zsh[4][64];
  int tid = threadIdx.x;
  int wid = tid >> 6, lane = tid & 63;
  int v0 = blockIdx.x * 4;
  zsh[wid][lane] = zt32[(size_t)v0 * 64 + tid];
  __syncthreads();

  int vec = v0 + wid;
  float zsq = zsq32[vec];
  const float* cdb = cdp + (size_t)vec * ncand;
  float dv0 = cdb[lane];
  float dv1 = (ncand > 64) ? cdb[lane + 64] : FLT_MAX;
  int j0 = lane, j1 = lane + 64;
  int ki0 = ((j0 >> 2) << 8) | (int)(__float_as_uint(dv0) & 0xFFu);
  int ki1 = ((j1 >> 2) << 8) | (int)(__float_as_uint(dv1) & 0xFFu);

  float dmin = fminf(dv0, dv1);
  #pragma unroll
  for (int m = 1; m < 64; m <<= 1) dmin = fminf(dmin, __shfl_xor(dmin, m, 64));
  float band = dmin + fmaf(sqrtf(zsq), 1.25e-5f, 1e-4f);

  const float* zw = zsh[wid];
  float d = FLT_MAX; int bi = 0x7fffffff;
  #pragma unroll
  for (int slot = 0; slot < 2; ++slot) {
    float dv = slot ? dv1 : dv0;
    int   kk = slot ? ki1 : ki0;
    if (dv <= band) {
      const float4* er = reinterpret_cast<const float4*>(emb + (size_t)kk * 64);
      float4 e4[16];
      #pragma unroll
      for (int i = 0; i < 16; ++i) e4[i] = er[i];
      float acc = 0.f;
      #pragma unroll
      for (int i = 0; i < 16; ++i) {               // exact ascending-c chain
        acc = __builtin_fmaf(zw[4 * i + 0], e4[i].x, acc);
        acc = __builtin_fmaf(zw[4 * i + 1], e4[i].y, acc);
        acc = __builtin_fmaf(zw[4 * i + 2], e4[i].z, acc);
        acc = __builtin_fmaf(zw[4 * i + 3], e4[i].w, acc);
      }
      float t1 = zsq + wsq32[kk];
      float dd = t1 - 2.0f * acc;
      if (dd < d || (dd == d && kk < bi)) { d = dd; bi = kk; }
    }
  }
  #pragma unroll
  for (int m = 1; m < 64; m <<= 1) {
    float od = __shfl_xor(d, m, 64);
    int   oi = __shfl_xor(bi, m, 64);
    if (od < d || (od == d && oi < bi)) { d = od; bi = oi; }
  }
  if (lane == 0) { pd[vec] = 0.f; pi[vec] = bi; }
}

// ---- fused ksplit-reduce + cubic upsample ----
__global__ __launch_bounds__(256) void k_up(
    const float* __restrict__ pd, const int* __restrict__ pi,
    const float* __restrict__ emb, float* __restrict__ hup,
    int pn, int ksplit) {
  __shared__ float td[256];
  __shared__ int   ti[256];
  __shared__ int   tok_s[256];
  __shared__ float wsh[16][4];
  __shared__ int   i0sh[16];

  int t = threadIdx.x;
  int i = blockIdx.x * 256 + t;
  int p = i & 255; int c = (i >> 8) & 63; int b = i >> 14;
  int P = pn * pn;
  int numVec = BB * P;
  int R = 256 / P;
  int v = t % P, sg = t / P;

  float bd = FLT_MAX; int bi = 0x7fffffff;
  for (int s = sg; s < ksplit; s += R) {
    float cd = pd[s * numVec + b * P + v]; int ci = pi[s * numVec + b * P + v];
    if (cd < bd || (cd == bd && ci < bi)) { bd = cd; bi = ci; }
  }
  td[t] = bd; ti[t] = bi;
  __syncthreads();
  for (int r = R >> 1; r >= 1; r >>= 1) {
    if (sg < r) {
      float cd = td[t + r * P]; int ci = ti[t + r * P];
      if (cd < td[t] || (cd == td[t] && ci < ti[t])) { td[t] = cd; ti[t] = ci; }
    }
    __syncthreads();
  }
  if (t < P) tok_s[t] = ti[t];
  if (pn < 16 && t < 16) {
    double s = (t + 0.5) * ((double)pn / 16.0) - 0.5;
    int i0 = (int)floor(s) - 1;
    int hi = pn - 4; if (hi < 0) hi = 0;
    if (i0 < 0) i0 = 0; if (i0 > hi) i0 = hi;
    double wv[4]; double sum = 0.0;
    #pragma unroll
    for (int qq = 0; qq < 4; ++qq) {
      int ii = i0 + qq;
      double w = 0.0;
      if (ii < pn) {
        double xx = fabs(s - (double)ii);
        if (xx < 1.0)       w = ((1.5 * xx - 2.5) * xx) * xx + 1.0;
        else if (xx < 2.0)  w = ((-0.5 * xx + 2.5) * xx - 4.0) * xx + 2.0;
      }
      wv[qq] = w; sum += w;
    }
    i0sh[t] = i0;
    #pragma unroll
    for (int qq = 0; qq < 4; ++qq) wsh[t][qq] = (float)(wv[qq] / sum);
  }
  __syncthreads();

  if (pn == 16) { hup[i] = emb[(size_t)tok_s[p] * 64 + c]; return; }

  int y = p >> 4, x = p & 15;
  int iy0 = i0sh[y], ix0 = i0sh[x];
  float acc = 0.f;
  #pragma unroll
  for (int ty = 0; ty < 4; ++ty) {
    float wy = wsh[y][ty];
    int iy = iy0 + ty; if (iy > pn - 1) iy = pn - 1;
    float tmp = 0.f;
    #pragma unroll
    for (int tx = 0; tx < 4; ++tx) {
      float wx = wsh[x][tx];
      int ix = ix0 + tx; if (ix > pn - 1) ix = pn - 1;
      tmp += wx * emb[(size_t)tok_s[iy * pn + ix] * 64 + c];
    }
    acc += wy * tmp;
  }
  hup[i] = acc;
}

// ---- conv (round-8 proven version) ----
__global__ __launch_bounds__(256) void k_conv(
    const float* __restrict__ hup, const float* __restrict__ w,
    const float* __restrict__ bias, float* __restrict__ out, float* __restrict__ zr) {
  __shared__ __align__(16) float ins[16][18 * 18];
  __shared__ __align__(16) float wsh[8 * 64 * 12];
  int tid = threadIdx.x;
  int b = blockIdx.x;
  int ocb = blockIdx.y;

  for (int idx = tid; idx < 16 * 324; idx += 256)
    (&ins[0][0])[idx] = 0.f;
  for (int idx = tid; idx < 8 * 64 * 9; idx += 256) {
    int ocic = idx / 9, t = idx - ocic * 9;
    wsh[ocic * 12 + t] = w[(size_t)ocb * 8 * 64 * 9 + idx];
  }

  const int wid = tid >> 6, lane = tid & 63;
  const int ocg = wid >> 1;
  const int ph = (wid & 1) * 64 + lane;
  const int x = ph & 15, y2 = ph >> 4;

  float acc[4][2];
  #pragma unroll
  for (int j = 0; j < 4; ++j) {
    float bv = bias[ocb * 8 + ocg * 4 + j];
    acc[j][0] = bv; acc[j][1] = bv;
  }

  const float* hb = hup + (size_t)b * 64 * NPIX;
  float sreg[16];
  #pragma unroll
  for (int r = 0; r < 16; ++r) sreg[r] = hb[r * 256 + tid];

  for (int cc = 0; cc < 4; ++cc) {
    __syncthreads();
    #pragma unroll
    for (int r = 0; r < 16; ++r) {
      int idx = r * 256 + tid;
      int icl = idx >> 8, p = idx & 255;
      ins[icl][((p >> 4) + 1) * 18 + (p & 15) + 1] = sreg[r];
    }
    __syncthreads();
    if (cc < 3) {
      #pragma unroll
      for (int r = 0; r < 16; ++r) sreg[r] = hb[(cc + 1) * 4096 + r * 256 + tid];
    }

    #pragma unroll 2
    for (int icl = 0; icl < 16; ++icl) {
      float vt[4][3];
      const float* ip = &ins[icl][y2 * 2 * 18 + x];
      #pragma unroll
      for (int r = 0; r < 4; ++r)
        #pragma unroll
        for (int cxx = 0; cxx < 3; ++cxx)
          vt[r][cxx] = ip[r * 18 + cxx];

      int ic = cc * 16 + icl;
      #pragma unroll
      for (int j = 0; j < 4; ++j) {
        const float* wp = &wsh[((ocg * 4 + j) * 64 + ic) * 12];
        float4 wa = *reinterpret_cast<const float4*>(wp);
        float4 wb = *reinterpret_cast<const float4*>(wp + 4);
        float w8 = wp[8];
        float wv[9] = {wa.x, wa.y, wa.z, wa.w, wb.x, wb.y, wb.z, wb.w, w8};
        float a0 = acc[j][0], a1 = acc[j][1];
        #pragma unroll
        for (int dy = 0; dy < 3; ++dy)
          #pragma unroll
          for (int dx = 0; dx < 3; ++dx) {
            float wt = wv[dy * 3 + dx];
            a0 = __builtin_fmaf(vt[dy][dx], wt, a0);
            a1 = __builtin_fmaf(vt[dy + 1][dx], wt, a1);
          }
        acc[j][0] = a0; acc[j][1] = a1;
      }
    }
  }

  #pragma unroll
  for (int j = 0; j < 4; ++j) {
    int oc = ocb * 8 + ocg * 4 + j;
    #pragma unroll
    for (int r = 0; r < 2; ++r) {
      size_t gi = ((size_t)b * 64 + oc) * NPIX + (y2 * 2 + r) * 16 + x;
      float h = hup[gi];
      float ho = 0.5f * h + 0.5f * acc[j][r];
      out[gi] += ho;
      zr[gi]  -= ho;
    }
  }
}

extern "C" void kernel_launch(void* const* d_in, const int* in_sizes, int n_in,
                              void* d_out, int out_size, void* d_ws, size_t ws_size,
                              hipStream_t stream) {
  const float* f    = (const float*)d_in[0];
  const float* emb  = (const float*)d_in[1];
  const float* phiw = (const float*)d_in[2];
  const float* phib = (const float*)d_in[3];
  float* out = (float*)d_out;

  float* ws  = (float*)d_ws;
  float* zr     = ws;                        // 524288
  float* zd     = ws + 524288;               // 32768 (si<=2 only)
  float* hup    = ws + 557056;               // 524288
  float* wsq32  = ws + 1081344;              // 8192
  float* pd     = ws + 1089536;              // 8192
  int*   pi     = (int*)(ws + 1097728);      // 8192
  u16*   zhi    = (u16*)(ws + 1105920);      // 524288 u16 = 262144 f
  u16*   ehi    = (u16*)(ws + 1368064);      // 524288 u16 = 262144 f
  float* cand_d = ws + 1630208;              // 1048576 (8192 vec x 128 keys)
  float* zsq32  = ws + 2678784;              // 8192
  float* zt32   = ws + 2686976;              // 524288
  // end 3211264 floats = 12.85 MB

  // PHI_IDX (numpy linspace argmin in doubles)
  double start = 1.0 / 3.0 / 4.0;
  double stop  = 1.0 - 1.0 / 3.0 / 4.0;
  double step  = (stop - start) / 3.0;
  double ticks[4] = { start, 1.0 * step + start, 2.0 * step + start, stop };
  int phi_idx[5];
  for (int si = 0; si < 5; ++si) {
    double xx = si / 4.0;
    int bj = 0; double bdd = fabs(ticks[0] - xx);
    for (int j = 1; j < 4; ++j) { double dd = fabs(ticks[j] - xx); if (dd < bdd) { bdd = dd; bj = j; } }
    phi_idx[si] = bj;
  }

  static const int MSarr[5] = {1, 2, 4, 8, 16};

  k_prep<<<NELEM / 256, 256, 0, stream>>>(f, zr, out, emb, wsq32, ehi);

  // si<=2: exact-path ksplits; si>=3: MFMA parts (part=256, ncand=128)
  const int KS[5] = {128, 32, 16, 32, 32};
  for (int si = 0; si < 5; ++si) {
    int pn = MSarr[si], pnpn = pn * pn, numVec = BB * pnpn;
    int ksplit = KS[si];
    if (si >= 3) {
      int bs = 16 / pn;                       // 2 (si3) or 1 (si4)
      int part = KK / ksplit;                 // 256
      k_pack<<<numVec / 4, 256, 0, stream>>>(zr, pn, bs, zhi, zt32, zsq32);
      dim3 g(numVec / 128, ksplit);
      k_argmin_mfma<<<g, 256, 0, stream>>>(zhi, ehi, wsq32, cand_d, numVec, part);
      k_rescore<<<numVec / 4, 256, 0, stream>>>(cand_d, zt32, emb,
                                                wsq32, zsq32, pd, pi,
                                                numVec, ksplit * 4);
      k_up<<<NELEM / 256, 256, 0, stream>>>(pd, pi, emb, hup, pn, 1);
    } else {
      int n = BB * CC * pnpn;
      k_down<<<(n + 255) / 256, 256, 0, stream>>>(zr, zd, pn);
      int kchunk = KK / ksplit;
      dim3 g((numVec + 31) / 32, ksplit);
      k_argmin<<<g, 256, 0, stream>>>(zd, emb, wsq32, pd, pi, numVec, pnpn, kchunk);
      k_up<<<NELEM / 256, 256, 0, stream>>>(pd, pi, emb, hup, pn, ksplit);
    }
    int pidx = phi_idx[si];
    k_conv<<<dim3(BB, 8), 256, 0, stream>>>(hup, phiw + pidx * 64 * 64 * 9,
                                            phib + pidx * 64, out, zr);
  }
}

// Round 14
// 311.979 us; speedup vs baseline: 1.7096x; 1.0451x over previous
//
#include <hip/hip_runtime.h>
#include <math.h>
#include <float.h>

#define BB 32
#define CC 64
#define KK 8192
#define NPIX 256
#define NELEM (BB*CC*NPIX)  // 524288

typedef unsigned short u16;
typedef __attribute__((ext_vector_type(8))) short bf16x8;
typedef __attribute__((ext_vector_type(4))) float f32x4;

__device__ __forceinline__ u16 f2bf(float v) {   // RNE f32->bf16
  unsigned u = __float_as_uint(v);
  return (u16)((u + 0x7FFFu + ((u >> 16) & 1u)) >> 16);
}

// init zr/out + wsq + ehi(bf16 pack of emb) in one launch
__global__ void k_prep(const float* __restrict__ f, float* __restrict__ zr,
                       float* __restrict__ out, const float* __restrict__ emb,
                       float* __restrict__ wsq32, u16* __restrict__ ehi) {
  int i = blockIdx.x * 256 + threadIdx.x;
  if (i < NELEM) { zr[i] = f[i]; out[i] = 0.f; ehi[i] = f2bf(emb[i]); }
  if (i < KK) {
    const float* row = emb + i * 64;
    double s = 0.0;
    #pragma unroll
    for (int c = 0; c < 64; ++c) s += (double)row[c] * (double)row[c];
    wsq32[i] = (float)s;   // same-binade f32: argmin-safe (scheme-free)
  }
}

// numpy-exact area mean for small scales (pn<=4): feeds exact argmin path
__global__ void k_down(const float* __restrict__ zr, float* __restrict__ zd, int pn) {
#pragma clang fp contract(off)
  int i = blockIdx.x * 256 + threadIdx.x;
  int pnpn = pn * pn;
  int n = BB * CC * pnpn;
  if (i >= n) return;
  int x = i % pn; int y = (i / pn) % pn; int bc = i / pnpn;
  int bs = 16 / pn;
  const float* src = zr + bc * NPIX + (y * bs) * 16 + x * bs;
  float acc = 0.f;
  for (int dy = 0; dy < bs; ++dy) {
    const float* a = src + dy * 16;
    float s;
    if (bs == 16) {
      float r[8];
      #pragma unroll
      for (int j = 0; j < 8; ++j) r[j] = a[j] + a[8 + j];
      s = ((r[0] + r[1]) + (r[2] + r[3])) + ((r[4] + r[5]) + (r[6] + r[7]));
    } else if (bs == 8) {
      s = ((a[0] + a[1]) + (a[2] + a[3])) + ((a[4] + a[5]) + (a[6] + a[7]));
    } else if (bs == 4) {
      s = ((a[0] + a[1]) + a[2]) + a[3];
    } else {
      s = a[0] + a[1];
    }
    acc = acc + s;
  }
  zd[i] = acc * (1.f / (bs * bs));
}

// pack for MFMA path: lane-per-channel. bs=1 (si4) or bs=2 (si3, fused
// numpy-exact 2x2 area mean). Writes zhi(bf16), zt32(f32), zsq32.
__global__ __launch_bounds__(256) void k_pack(
    const float* __restrict__ zr, int pn, int bs,
    u16* __restrict__ zhi, float* __restrict__ zt32, float* __restrict__ zsq32) {
#pragma clang fp contract(off)
  int tid = threadIdx.x;
  int lv = tid >> 6, c = tid & 63;
  int vec = blockIdx.x * 4 + lv;
  int pnpn = pn * pn;
  int b = vec / pnpn, p = vec % pnpn;
  int y = p / pn, x = p % pn;
  const float* src = zr + ((size_t)(b * 64 + c)) * 256 + (y * bs) * 16 + x * bs;
  float v;
  if (bs == 1) {
    v = src[0];
  } else {           // bs==2: (a00+a01) + (a10+a11), * exact 0.25
    v = (src[0] + src[1]) + (src[16] + src[17]);
    v = v * 0.25f;
  }
  zhi[(size_t)vec * 64 + c] = f2bf(v);
  zt32[(size_t)vec * 64 + c] = v;
  double sq = (double)v * (double)v;
  #pragma unroll
  for (int m = 1; m < 64; m <<= 1)
    sq += __shfl_xor(sq, m, 64);        // f64 all-reduce: order-independent to 1e-15
  if (c == 0) zsq32[vec] = (float)sq;
}

// ---- argmin, small scales (exact path, proven) ----
__global__ __launch_bounds__(256, 4) void k_argmin(
    const float* __restrict__ zd, const float* __restrict__ emb,
    const float* __restrict__ wsq32,
    float* __restrict__ pd, int* __restrict__ pi,
    int numVec, int pnpn, int kchunk) {
#pragma clang fp contract(off)
  __shared__ __align__(16) float zt[32][68];
  __shared__ __align__(16) float et[64 * 64];
  __shared__ float ws_s[64];
  __shared__ float red_d[256];
  __shared__ int   red_i[256];
  int tid = threadIdx.x;
  int v0 = blockIdx.x * 32;
  int kbase = blockIdx.y * kchunk;

  for (int idx = tid; idx < 32 * 64; idx += 256) {
    int v = idx >> 6, c = idx & 63;
    int vi = v0 + v;
    float val = 0.f;
    if (vi < numVec) {
      int b = vi / pnpn, p = vi % pnpn;
      val = zd[(b * 64 + c) * pnpn + p];
    }
    zt[v][c] = val;
  }
  __syncthreads();

  const int v = tid & 31, kg = tid >> 5;
  float4 z4[16];
  #pragma unroll
  for (int i = 0; i < 16; ++i) z4[i] = *reinterpret_cast<float4*>(&zt[v][i * 4]);
  float zsq = 0.f;
  #pragma unroll
  for (int i = 0; i < 16; ++i)
    zsq += z4[i].x * z4[i].x + z4[i].y * z4[i].y + z4[i].z * z4[i].z + z4[i].w * z4[i].w;

  float bd = FLT_MAX; int bi = 0x7fffffff;
  for (int k0 = 0; k0 < kchunk; k0 += 64) {
    __syncthreads();
    {
      const float4* gsrc = reinterpret_cast<const float4*>(emb + (size_t)(kbase + k0) * 64);
      float4* ldst = reinterpret_cast<float4*>(et);
      #pragma unroll
      for (int idx = 0; idx < 4; ++idx)
        ldst[tid + idx * 256] = gsrc[tid + idx * 256];
    }
    if (tid < 64) ws_s[tid] = wsq32[kbase + k0 + tid];
    __syncthreads();
    #pragma unroll
    for (int j = 0; j < 8; ++j) {
      int kl = kg * 8 + j;
      const float4* e4 = reinterpret_cast<const float4*>(&et[kl * 64]);
      float acc = 0.f;
      #pragma unroll
      for (int i = 0; i < 16; ++i) {
        float4 e = e4[i];
        acc = __builtin_fmaf(z4[i].x, e.x, acc);
        acc = __builtin_fmaf(z4[i].y, e.y, acc);
        acc = __builtin_fmaf(z4[i].z, e.z, acc);
        acc = __builtin_fmaf(z4[i].w, e.w, acc);
      }
      float t1 = zsq + ws_s[kl];
      float d  = t1 - 2.0f * acc;
      if (d < bd) { bd = d; bi = kbase + k0 + kl; }
    }
  }
  red_d[tid] = bd; red_i[tid] = bi;
  __syncthreads();
  if (tid < 32) {
    float fb = red_d[tid]; int fi = red_i[tid];
    #pragma unroll
    for (int g = 1; g < 8; ++g) {
      float cd = red_d[g * 32 + tid]; int ci = red_i[g * 32 + tid];
      if (cd < fb || (cd == fb && ci < fi)) { fb = cd; fi = ci; }
    }
    int vi = v0 + tid;
    if (vi < numVec) {
      pd[blockIdx.y * numVec + vi] = fb;
      pi[blockIdx.y * numVec + vi] = fi;
    }
  }
}

// ---- argmin big scales: bf16 MFMA prefilter, MAX-form packed keys.
// acc init = -wl/2, MFMA gives (dot - wl/2); argmin(wl-2dot) == argmax(acc).
// key = (acc & 0xFFFFFF00) | id (id = code idx in part, 8 bits).
// top-2/lane via fmax+med3; merge = top-2 per 8-lane half (3-step butterfly).
__global__ __launch_bounds__(256, 8) void k_argmin_mfma(
    const u16* __restrict__ zhi, const u16* __restrict__ ehi,
    const float* __restrict__ wsq32, float* __restrict__ cdp,
    int numVec, int part) {
  __shared__ u16  es[2][64 * 72];
  __shared__ float wss[2][64];
  const int tid = threadIdx.x;
  const int wid = tid >> 6, lane = tid & 63;
  const int l15 = lane & 15, l4 = lane >> 4;
  const int vw = blockIdx.x * 128 + wid * 32;
  const int kbase = blockIdx.y * part;
  const int KSx = gridDim.y;

  bf16x8 za[2][2];
  #pragma unroll
  for (int s = 0; s < 2; ++s) {
    const u16* zp = zhi + (size_t)(vw + s * 16 + l15) * 64 + l4 * 8;
    za[s][0] = *reinterpret_cast<const bf16x8*>(zp);
    za[s][1] = *reinterpret_cast<const bf16x8*>(zp + 32);
  }

  float d1[2][4], d2[2][4];
  #pragma unroll
  for (int s = 0; s < 2; ++s)
    #pragma unroll
    for (int r = 0; r < 4; ++r) { d1[s][r] = -FLT_MAX; d2[s][r] = -FLT_MAX; }

  const int NT = part >> 6;
  #define STAGE(buf, t)                                                      \
    { const u16* src = ehi + (size_t)(kbase + (t) * 64) * 64;                \
      int code = tid >> 2, seg = tid & 3;                                    \
      const bf16x8* s8 = reinterpret_cast<const bf16x8*>(src + code * 64 + seg * 16); \
      bf16x8 v0 = s8[0], v1 = s8[1];                                         \
      bf16x8* d8 = reinterpret_cast<bf16x8*>(&es[buf][code * 72 + seg * 16]);\
      d8[0] = v0; d8[1] = v1;                                                \
      if (tid < 64) wss[buf][tid] = wsq32[kbase + (t) * 64 + tid]; }

  STAGE(0, 0);
  __syncthreads();
  for (int t = 0; t < NT; ++t) {
    int cur = t & 1;
    if (t + 1 < NT) { STAGE(cur ^ 1, t + 1); }
    #pragma unroll
    for (int ct = 0; ct < 4; ++ct) {
      const u16* eb = &es[cur][(ct * 16 + l15) * 72 + l4 * 8];
      bf16x8 b0 = *reinterpret_cast<const bf16x8*>(eb);
      bf16x8 b1 = *reinterpret_cast<const bf16x8*>(eb + 32);
      float hwl = -0.5f * wss[cur][ct * 16 + l15];
      unsigned idu = (unsigned)(t * 64 + ct * 16 + l15);   // < 256
      #pragma unroll
      for (int s = 0; s < 2; ++s) {
        f32x4 acc = {hwl, hwl, hwl, hwl};
        acc = __builtin_amdgcn_mfma_f32_16x16x32_bf16(za[s][0], b0, acc, 0, 0, 0);
        acc = __builtin_amdgcn_mfma_f32_16x16x32_bf16(za[s][1], b1, acc, 0, 0, 0);
        #pragma unroll
        for (int r = 0; r < 4; ++r) {
          float key = __uint_as_float((__float_as_uint(acc[r]) & 0xFFFFFF00u) | idu);
          float o1 = d1[s][r];
          d1[s][r] = fmaxf(o1, key);
          d2[s][r] = __builtin_amdgcn_fmed3f(o1, key, d2[s][r]);
        }
      }
    }
    __syncthreads();
  }

  // merge: top-2 per 8-lane half (masks 1,2,4), write 4 keys/part
  #pragma unroll
  for (int s = 0; s < 2; ++s)
    #pragma unroll
    for (int r = 0; r < 4; ++r) {
      float q0 = d1[s][r], q1 = d2[s][r];
      #pragma unroll
      for (int m = 1; m < 8; m <<= 1) {
        float p0 = __shfl_xor(q0, m), p1 = __shfl_xor(q1, m);
        { bool c0 = p0 > q0, c1 = p0 > q1;
          q1 = c0 ? q0 : (c1 ? p0 : q1);
          q0 = c0 ? p0 : q0; }
        { bool c0 = p1 > q0, c1 = p1 > q1;
          q1 = c0 ? q0 : (c1 ? p1 : q1);
          q0 = c0 ? p1 : q0; }
      }
      if ((l15 & 7) == 0) {
        int vec = vw + s * 16 + l4 * 4 + r;
        int half = l15 >> 3;
        size_t base = ((size_t)vec * KSx + blockIdx.y) * 4 + half * 2;
        cdp[base + 0] = q0; cdp[base + 1] = q1;
      }
    }
}

// exact rescore: wave-per-vector, lane-per-candidate (2 slots, ncand=128).
// keys are MAX-form (acc = dot - wl/2); band: key >= amax - band/2.
__global__ __launch_bounds__(256) void k_rescore(
    const float* __restrict__ cdp, const float* __restrict__ zt32,
    const float* __restrict__ emb, const float* __restrict__ wsq32,
    const float* __restrict__ zsq32,
    float* __restrict__ pd, int* __restrict__ pi,
    int numVec, int ncand) {
#pragma clang fp contract(off)
  __shared__ float zsh[4][64];
  int tid = threadIdx.x;
  int wid = tid >> 6, lane = tid & 63;
  int v0 = blockIdx.x * 4;
  zsh[wid][lane] = zt32[(size_t)v0 * 64 + tid];
  __syncthreads();

  int vec = v0 + wid;
  float zsq = zsq32[vec];
  const float* cdb = cdp + (size_t)vec * ncand;
  float dv0 = cdb[lane];
  float dv1 = (ncand > 64) ? cdb[lane + 64] : -FLT_MAX;
  int j0 = lane, j1 = lane + 64;
  int ki0 = ((j0 >> 2) << 8) | (int)(__float_as_uint(dv0) & 0xFFu);
  int ki1 = ((j1 >> 2) << 8) | (int)(__float_as_uint(dv1) & 0xFFu);

  float amax = fmaxf(dv0, dv1);
  #pragma unroll
  for (int m = 1; m < 64; m <<= 1) amax = fmaxf(amax, __shfl_xor(amax, m, 64));
  float thr = amax - 0.5f * fmaf(sqrtf(zsq), 1.25e-5f, 1e-4f);

  const float* zw = zsh[wid];
  float d = FLT_MAX; int bi = 0x7fffffff;
  #pragma unroll
  for (int slot = 0; slot < 2; ++slot) {
    float dv = slot ? dv1 : dv0;
    int   kk = slot ? ki1 : ki0;
    if (dv >= thr) {
      const float4* er = reinterpret_cast<const float4*>(emb + (size_t)kk * 64);
      float4 e4[16];
      #pragma unroll
      for (int i = 0; i < 16; ++i) e4[i] = er[i];
      float acc = 0.f;
      #pragma unroll
      for (int i = 0; i < 16; ++i) {               // exact ascending-c chain
        acc = __builtin_fmaf(zw[4 * i + 0], e4[i].x, acc);
        acc = __builtin_fmaf(zw[4 * i + 1], e4[i].y, acc);
        acc = __builtin_fmaf(zw[4 * i + 2], e4[i].z, acc);
        acc = __builtin_fmaf(zw[4 * i + 3], e4[i].w, acc);
      }
      float t1 = zsq + wsq32[kk];
      float dd = t1 - 2.0f * acc;
      if (dd < d || (dd == d && kk < bi)) { d = dd; bi = kk; }
    }
  }
  #pragma unroll
  for (int m = 1; m < 64; m <<= 1) {
    float od = __shfl_xor(d, m, 64);
    int   oi = __shfl_xor(bi, m, 64);
    if (od < d || (od == d && oi < bi)) { d = od; bi = oi; }
  }
  if (lane == 0) { pd[vec] = 0.f; pi[vec] = bi; }
}

// ---- fused ksplit-reduce + cubic upsample ----
__global__ __launch_bounds__(256) void k_up(
    const float* __restrict__ pd, const int* __restrict__ pi,
    const float* __restrict__ emb, float* __restrict__ hup,
    int pn, int ksplit) {
  __shared__ float td[256];
  __shared__ int   ti[256];
  __shared__ int   tok_s[256];
  __shared__ float wsh[16][4];
  __shared__ int   i0sh[16];

  int t = threadIdx.x;
  int i = blockIdx.x * 256 + t;
  int p = i & 255; int c = (i >> 8) & 63; int b = i >> 14;
  int P = pn * pn;
  int numVec = BB * P;
  int R = 256 / P;
  int v = t % P, sg = t / P;

  float bd = FLT_MAX; int bi = 0x7fffffff;
  for (int s = sg; s < ksplit; s += R) {
    float cd = pd[s * numVec + b * P + v]; int ci = pi[s * numVec + b * P + v];
    if (cd < bd || (cd == bd && ci < bi)) { bd = cd; bi = ci; }
  }
  td[t] = bd; ti[t] = bi;
  __syncthreads();
  for (int r = R >> 1; r >= 1; r >>= 1) {
    if (sg < r) {
      float cd = td[t + r * P]; int ci = ti[t + r * P];
      if (cd < td[t] || (cd == td[t] && ci < ti[t])) { td[t] = cd; ti[t] = ci; }
    }
    __syncthreads();
  }
  if (t < P) tok_s[t] = ti[t];
  if (pn < 16 && t < 16) {
    double s = (t + 0.5) * ((double)pn / 16.0) - 0.5;
    int i0 = (int)floor(s) - 1;
    int hi = pn - 4; if (hi < 0) hi = 0;
    if (i0 < 0) i0 = 0; if (i0 > hi) i0 = hi;
    double wv[4]; double sum = 0.0;
    #pragma unroll
    for (int qq = 0; qq < 4; ++qq) {
      int ii = i0 + qq;
      double w = 0.0;
      if (ii < pn) {
        double xx = fabs(s - (double)ii);
        if (xx < 1.0)       w = ((1.5 * xx - 2.5) * xx) * xx + 1.0;
        else if (xx < 2.0)  w = ((-0.5 * xx + 2.5) * xx - 4.0) * xx + 2.0;
      }
      wv[qq] = w; sum += w;
    }
    i0sh[t] = i0;
    #pragma unroll
    for (int qq = 0; qq < 4; ++qq) wsh[t][qq] = (float)(wv[qq] / sum);
  }
  __syncthreads();

  if (pn == 16) { hup[i] = emb[(size_t)tok_s[p] * 64 + c]; return; }

  int y = p >> 4, x = p & 15;
  int iy0 = i0sh[y], ix0 = i0sh[x];
  float acc = 0.f;
  #pragma unroll
  for (int ty = 0; ty < 4; ++ty) {
    float wy = wsh[y][ty];
    int iy = iy0 + ty; if (iy > pn - 1) iy = pn - 1;
    float tmp = 0.f;
    #pragma unroll
    for (int tx = 0; tx < 4; ++tx) {
      float wx = wsh[x][tx];
      int ix = ix0 + tx; if (ix > pn - 1) ix = pn - 1;
      tmp += wx * emb[(size_t)tok_s[iy * pn + ix] * 64 + c];
    }
    acc += wy * tmp;
  }
  hup[i] = acc;
}

// ---- conv (round-8 proven version) ----
__global__ __launch_bounds__(256) void k_conv(
    const float* __restrict__ hup, const float* __restrict__ w,
    const float* __restrict__ bias, float* __restrict__ out, float* __restrict__ zr) {
  __shared__ __align__(16) float ins[16][18 * 18];
  __shared__ __align__(16) float wsh[8 * 64 * 12];
  int tid = threadIdx.x;
  int b = blockIdx.x;
  int ocb = blockIdx.y;

  for (int idx = tid; idx < 16 * 324; idx += 256)
    (&ins[0][0])[idx] = 0.f;
  for (int idx = tid; idx < 8 * 64 * 9; idx += 256) {
    int ocic = idx / 9, t = idx - ocic * 9;
    wsh[ocic * 12 + t] = w[(size_t)ocb * 8 * 64 * 9 + idx];
  }

  const int wid = tid >> 6, lane = tid & 63;
  const int ocg = wid >> 1;
  const int ph = (wid & 1) * 64 + lane;
  const int x = ph & 15, y2 = ph >> 4;

  float acc[4][2];
  #pragma unroll
  for (int j = 0; j < 4; ++j) {
    float bv = bias[ocb * 8 + ocg * 4 + j];
    acc[j][0] = bv; acc[j][1] = bv;
  }

  const float* hb = hup + (size_t)b * 64 * NPIX;
  float sreg[16];
  #pragma unroll
  for (int r = 0; r < 16; ++r) sreg[r] = hb[r * 256 + tid];

  for (int cc = 0; cc < 4; ++cc) {
    __syncthreads();
    #pragma unroll
    for (int r = 0; r < 16; ++r) {
      int idx = r * 256 + tid;
      int icl = idx >> 8, p = idx & 255;
      ins[icl][((p >> 4) + 1) * 18 + (p & 15) + 1] = sreg[r];
    }
    __syncthreads();
    if (cc < 3) {
      #pragma unroll
      for (int r = 0; r < 16; ++r) sreg[r] = hb[(cc + 1) * 4096 + r * 256 + tid];
    }

    #pragma unroll 2
    for (int icl = 0; icl < 16; ++icl) {
      float vt[4][3];
      const float* ip = &ins[icl][y2 * 2 * 18 + x];
      #pragma unroll
      for (int r = 0; r < 4; ++r)
        #pragma unroll
        for (int cxx = 0; cxx < 3; ++cxx)
          vt[r][cxx] = ip[r * 18 + cxx];

      int ic = cc * 16 + icl;
      #pragma unroll
      for (int j = 0; j < 4; ++j) {
        const float* wp = &wsh[((ocg * 4 + j) * 64 + ic) * 12];
        float4 wa = *reinterpret_cast<const float4*>(wp);
        float4 wb = *reinterpret_cast<const float4*>(wp + 4);
        float w8 = wp[8];
        float wv[9] = {wa.x, wa.y, wa.z, wa.w, wb.x, wb.y, wb.z, wb.w, w8};
        float a0 = acc[j][0], a1 = acc[j][1];
        #pragma unroll
        for (int dy = 0; dy < 3; ++dy)
          #pragma unroll
          for (int dx = 0; dx < 3; ++dx) {
            float wt = wv[dy * 3 + dx];
            a0 = __builtin_fmaf(vt[dy][dx], wt, a0);
            a1 = __builtin_fmaf(vt[dy + 1][dx], wt, a1);
          }
        acc[j][0] = a0; acc[j][1] = a1;
      }
    }
  }

  #pragma unroll
  for (int j = 0; j < 4; ++j) {
    int oc = ocb * 8 + ocg * 4 + j;
    #pragma unroll
    for (int r = 0; r < 2; ++r) {
      size_t gi = ((size_t)b * 64 + oc) * NPIX + (y2 * 2 + r) * 16 + x;
      float h = hup[gi];
      float ho = 0.5f * h + 0.5f * acc[j][r];
      out[gi] += ho;
      zr[gi]  -= ho;
    }
  }
}

extern "C" void kernel_launch(void* const* d_in, const int* in_sizes, int n_in,
                              void* d_out, int out_size, void* d_ws, size_t ws_size,
                              hipStream_t stream) {
  const float* f    = (const float*)d_in[0];
  const float* emb  = (const float*)d_in[1];
  const float* phiw = (const float*)d_in[2];
  const float* phib = (const float*)d_in[3];
  float* out = (float*)d_out;

  float* ws  = (float*)d_ws;
  float* zr     = ws;                        // 524288
  float* zd     = ws + 524288;               // 32768 (si<=2 only)
  float* hup    = ws + 557056;               // 524288
  float* wsq32  = ws + 1081344;              // 8192
  float* pd     = ws + 1089536;              // 8192
  int*   pi     = (int*)(ws + 1097728);      // 8192
  u16*   zhi    = (u16*)(ws + 1105920);      // 524288 u16 = 262144 f
  u16*   ehi    = (u16*)(ws + 1368064);      // 524288 u16 = 262144 f
  float* cand_d = ws + 1630208;              // 1048576 (8192 vec x 128 keys)
  float* zsq32  = ws + 2678784;              // 8192
  float* zt32   = ws + 2686976;              // 524288
  // end 3211264 floats = 12.85 MB

  // PHI_IDX (numpy linspace argmin in doubles)
  double start = 1.0 / 3.0 / 4.0;
  double stop  = 1.0 - 1.0 / 3.0 / 4.0;
  double step  = (stop - start) / 3.0;
  double ticks[4] = { start, 1.0 * step + start, 2.0 * step + start, stop };
  int phi_idx[5];
  for (int si = 0; si < 5; ++si) {
    double xx = si / 4.0;
    int bj = 0; double bdd = fabs(ticks[0] - xx);
    for (int j = 1; j < 4; ++j) { double dd = fabs(ticks[j] - xx); if (dd < bdd) { bdd = dd; bj = j; } }
    phi_idx[si] = bj;
  }

  static const int MSarr[5] = {1, 2, 4, 8, 16};

  k_prep<<<NELEM / 256, 256, 0, stream>>>(f, zr, out, emb, wsq32, ehi);

  // si<=2: exact-path ksplits; si>=3: MFMA parts (part=256, ncand=128)
  const int KS[5] = {128, 32, 16, 32, 32};
  for (int si = 0; si < 5; ++si) {
    int pn = MSarr[si], pnpn = pn * pn, numVec = BB * pnpn;
    int ksplit = KS[si];
    if (si >= 3) {
      int bs = 16 / pn;                       // 2 (si3) or 1 (si4)
      int part = KK / ksplit;                 // 256
      k_pack<<<numVec / 4, 256, 0, stream>>>(zr, pn, bs, zhi, zt32, zsq32);
      dim3 g(numVec / 128, ksplit);
      k_argmin_mfma<<<g, 256, 0, stream>>>(zhi, ehi, wsq32, cand_d, numVec, part);
      k_rescore<<<numVec / 4, 256, 0, stream>>>(cand_d, zt32, emb,
                                                wsq32, zsq32, pd, pi,
                                                numVec, ksplit * 4);
      k_up<<<NELEM / 256, 256, 0, stream>>>(pd, pi, emb, hup, pn, 1);
    } else {
      int n = BB * CC * pnpn;
      k_down<<<(n + 255) / 256, 256, 0, stream>>>(zr, zd, pn);
      int kchunk = KK / ksplit;
      dim3 g((numVec + 31) / 32, ksplit);
      k_argmin<<<g, 256, 0, stream>>>(zd, emb, wsq32, pd, pi, numVec, pnpn, kchunk);
      k_up<<<NELEM / 256, 256, 0, stream>>>(pd, pi, emb, hup, pn, ksplit);
    }
    int pidx = phi_idx[si];
    k_conv<<<dim3(BB, 8), 256, 0, stream>>>(hup, phiw + pidx * 64 * 64 * 9,
                                            phib + pidx * 64, out, zr);
  }
}